// Round 6
// baseline (1737.009 us; speedup 1.0000x reference)
//
#include <hip/hip_runtime.h>
#include <hip/hip_bf16.h>
#include <stdint.h>

// ---------------------------------------------------------------------------
// B=16, N=1024, D=256, M=128, C=8192. fp32 in/out, bf16 MFMA internally.
// Output: 3 x [B,N,D] fp32 concatenated.
// ---------------------------------------------------------------------------

namespace {
constexpr int B_ = 16;
constexpr int N_ = 1024;
constexpr int D_ = 256;
constexpr int M_ = 128;
constexpr int C_ = 8192;
constexpr int BN_ = B_ * N_;                       // 16384
constexpr long long BND_ = (long long)BN_ * D_;    // 4,194,304 elems
constexpr int NB_ = N_ * B_;                       // 16384
}

typedef short bf16x8_t __attribute__((ext_vector_type(8)));
typedef float f32x4_t __attribute__((ext_vector_type(4)));

#define DEV static __device__ __forceinline__
DEV float bf2f(unsigned short u) { return __uint_as_float((unsigned)u << 16); }
DEV unsigned short f2bf_bits(float x) { return __builtin_bit_cast(unsigned short, __float2bfloat16(x)); }

// ---------------------------------------------------------------------------
// NT bf16 MFMA GEMM, 128x128 tile, BK=32, 4 waves, software-pipelined staging.
// z decode: batch = z % zBatches; rem = z / zBatches; pi = rem&1 selects the
// (A0,B0)/(A1,B1) pair; kh = rem>>1 gives K-piece offset kh*kPiece.
// Output element: gidx = cOff + rem*pieceCs + batch*sC + row*ldc + col.
// epi: 0 = fp32 C = v            (v = acc*scale)
//      1 = bf16 C = v + bias[col]
//      2 = fp32 C = relu(v + bias[col] + add0..3[idx])   (adds nullable)
// ---------------------------------------------------------------------------
__global__ __launch_bounds__(256) void gemm_nt_kernel(
    const __hip_bfloat16* __restrict__ A0, const __hip_bfloat16* __restrict__ A1,
    int lda, long long sA,
    const __hip_bfloat16* __restrict__ B0, const __hip_bfloat16* __restrict__ B1,
    int ldb, long long sB,
    void* __restrict__ Cv, int ldc, long long sC, long long cOff, long long pieceCs,
    int K, int kPiece, int zBatches,
    float scale, const float* __restrict__ bias,
    const float* __restrict__ add0, const float* __restrict__ add1,
    const float* __restrict__ add2, const float* __restrict__ add3,
    int epi)
{
    __shared__ __align__(16) short smA[128 * 32];
    __shared__ __align__(16) short smB[128 * 32];

    const int tid = threadIdx.x;
    const int wid = tid >> 6;
    const int lane = tid & 63;
    const int z = blockIdx.z;
    const int batch = z % zBatches;
    const int rem = z / zBatches;
    const int pi = rem & 1;
    const int kh = rem >> 1;

    const short* Ab = (const short*)(pi ? A1 : A0) + (size_t)batch * sA
                    + (size_t)blockIdx.x * 128 * lda + (size_t)kh * kPiece;
    const short* Bb = (const short*)(pi ? B1 : B0) + (size_t)batch * sB
                    + (size_t)blockIdx.y * 128 * ldb + (size_t)kh * kPiece;

    const int wm = (wid >> 1) * 64;
    const int wn = (wid & 1) * 64;
    const int fr = lane & 15;            // fragment row (m or n)
    const int kq = (lane >> 4) * 8;      // k-offset of this lane's 8 elems
    const int sr = tid >> 2;             // staging row 0..63 (plus h*64)
    const int sc = (tid & 3) * 8;        // staging short-col

    f32x4_t acc[4][4] = {};
    int4 avv[2], bvv[2];
#pragma unroll
    for (int h = 0; h < 2; h++) {        // prologue: tile 0
        const int row = h * 64 + sr;
        avv[h] = *(const int4*)(Ab + (size_t)row * lda + sc);
        bvv[h] = *(const int4*)(Bb + (size_t)row * ldb + sc);
    }

    for (int k0 = 0; k0 < K; k0 += 32) {
        __syncthreads();                 // prior tile's ds_reads complete
#pragma unroll
        for (int h = 0; h < 2; h++) {
            const int row = h * 64 + sr;
            *(int4*)&smA[row * 32 + sc] = avv[h];
            *(int4*)&smB[row * 32 + sc] = bvv[h];
        }
        __syncthreads();

        const int kn = k0 + 32;          // prefetch next tile (overlaps MFMA)
        if (kn < K) {
#pragma unroll
            for (int h = 0; h < 2; h++) {
                const int row = h * 64 + sr;
                avv[h] = *(const int4*)(Ab + (size_t)row * lda + (kn + sc));
                bvv[h] = *(const int4*)(Bb + (size_t)row * ldb + (kn + sc));
            }
        }

        bf16x8_t af[4], bfv[4];
#pragma unroll
        for (int i = 0; i < 4; i++)
            af[i] = *(const bf16x8_t*)&smA[(wm + i * 16 + fr) * 32 + kq];
#pragma unroll
        for (int j = 0; j < 4; j++)
            bfv[j] = *(const bf16x8_t*)&smB[(wn + j * 16 + fr) * 32 + kq];
#pragma unroll
        for (int i = 0; i < 4; i++)
#pragma unroll
            for (int j = 0; j < 4; j++)
                acc[i][j] = __builtin_amdgcn_mfma_f32_16x16x32_bf16(af[i], bfv[j], acc[i][j], 0, 0, 0);
    }

    const int rb = (lane >> 4) * 4;
#pragma unroll
    for (int j = 0; j < 4; j++) {
        const int col = blockIdx.y * 128 + wn + j * 16 + fr;
        const float bv = bias ? bias[col] : 0.0f;
#pragma unroll
        for (int i = 0; i < 4; i++) {
#pragma unroll
            for (int r = 0; r < 4; r++) {
                const int row = blockIdx.x * 128 + wm + i * 16 + rb + r;
                const size_t idx = (size_t)batch * sC + (size_t)row * ldc + col;
                const size_t gidx = (size_t)cOff + (size_t)rem * pieceCs + idx;
                const float v = acc[i][j][r] * scale;
                if (epi == 0) {
                    ((float*)Cv)[gidx] = v;
                } else if (epi == 1) {
                    ((__hip_bfloat16*)Cv)[gidx] = __float2bfloat16(v + bv);
                } else {
                    float o = v + bv;
                    if (add0) o += add0[idx];
                    if (add1) o += add1[idx];
                    if (add2) o += add2[idx];
                    if (add3) o += add3[idx];
                    ((float*)Cv)[gidx] = o > 0.0f ? o : 0.0f;
                }
            }
        }
    }
}

// ---------------------------------------------------------------------------
// Weight convert+transpose, all 5 weights in one dispatch (z selects).
// ---------------------------------------------------------------------------
__global__ __launch_bounds__(256) void wt_transpose_kernel(
    const float* __restrict__ W0, const float* __restrict__ W1,
    const float* __restrict__ W2, const float* __restrict__ W3,
    const float* __restrict__ W4, __hip_bfloat16* __restrict__ out)
{
    const int z = blockIdx.z;
    const float* in = z == 0 ? W0 : z == 1 ? W1 : z == 2 ? W2 : z == 3 ? W3 : W4;
    __hip_bfloat16* o = out + (size_t)z * D_ * D_;
    __shared__ float t[32][33];
    const int r0 = blockIdx.x * 32, c0 = blockIdx.y * 32;
    const int tx = threadIdx.x & 31, ty = threadIdx.x >> 5;
#pragma unroll
    for (int k = 0; k < 4; k++) {
        int r = ty + k * 8;
        t[r][tx] = in[(size_t)(r0 + r) * D_ + (c0 + tx)];
    }
    __syncthreads();
#pragma unroll
    for (int k = 0; k < 4; k++) {
        int r = ty + k * 8;
        o[(size_t)(c0 + r) * D_ + (r0 + tx)] = __float2bfloat16(t[tx][r]);
    }
}

// bf16 transpose for V: out[c][r] = in[r][c], batched over z.
__global__ __launch_bounds__(256) void transpose_bf16_kernel(
    const __hip_bfloat16* __restrict__ in, __hip_bfloat16* __restrict__ out,
    int R, int Cc, long long sIn, long long sOut)
{
    __shared__ short t[32][33];
    const size_t bz = blockIdx.z;
    const short* I = (const short*)in + bz * (size_t)sIn;
    short* O = (short*)out + bz * (size_t)sOut;
    const int r0 = blockIdx.x * 32, c0 = blockIdx.y * 32;
    const int tx = threadIdx.x & 31, ty = threadIdx.x >> 5;
#pragma unroll
    for (int k = 0; k < 4; k++) {
        int r = ty + k * 8;
        t[r][tx] = I[(size_t)(r0 + r) * Cc + (c0 + tx)];
    }
    __syncthreads();
#pragma unroll
    for (int k = 0; k < 4; k++) {
        int r = ty + k * 8;
        O[(size_t)(c0 + r) * R + (r0 + tx)] = t[tx][r];
    }
}

// all 3 modality inputs fp32 -> bf16, one dispatch
__global__ void cvt3_kernel(const float* __restrict__ x0, const float* __restrict__ x1,
                            const float* __restrict__ x2, __hip_bfloat16* __restrict__ dst)
{
    const int z = blockIdx.z;
    const float* s = z == 0 ? x0 : z == 1 ? x1 : x2;
    const long long i = (long long)blockIdx.x * 256 + threadIdx.x;
    dst[(size_t)z * BND_ + i] = __float2bfloat16(s[i]);
}

__global__ void zero_kernel(float* __restrict__ p, int n)
{
    const int i = blockIdx.x * 256 + threadIdx.x;
    if (i < n) p[i] = 0.0f;
}

// ---------------------------------------------------------------------------
// Hypergraph pipeline, batched over 3 modalities via blockIdx.z
// ---------------------------------------------------------------------------
__global__ void hg_count_kernel(const int* __restrict__ i0, const int* __restrict__ i1,
                                const int* __restrict__ i2,
                                int* __restrict__ Ddeg, int* __restrict__ Edeg)
{
    const int z = blockIdx.z;
    const int* idx = z == 0 ? i0 : z == 1 ? i1 : i2;
    const int c = blockIdx.x * 256 + threadIdx.x;
    atomicAdd(&Ddeg[z * N_ + idx[c]], 1);
    atomicAdd(&Edeg[z * M_ + idx[C_ + c]], 1);
}

__global__ __launch_bounds__(1024) void hg_scan_kernel(
    const int* __restrict__ deg, int* __restrict__ offs,
    float* __restrict__ inv, int* __restrict__ cnt, int len)
{
    const int z = blockIdx.z;
    deg += z * len; offs += z * (len + 1); inv += z * len; cnt += z * len;
    __shared__ int tmp[1024];
    const int t = threadIdx.x;
    const int v = deg[t];
    tmp[t] = v;
    __syncthreads();
    for (int o = 1; o < len; o <<= 1) {
        int x = (t >= o) ? tmp[t - o] : 0;
        __syncthreads();
        tmp[t] += x;
        __syncthreads();
    }
    offs[t] = tmp[t] - v;
    if (t == len - 1) offs[len] = tmp[t];
    inv[t] = (v > 0) ? (1.0f / (float)v) : 0.0f;
    cnt[t] = 0;
}

__global__ void hg_fill_kernel(const int* __restrict__ i0, const int* __restrict__ i1,
                               const int* __restrict__ i2,
                               const int* __restrict__ noffs, const int* __restrict__ eoffs,
                               int* __restrict__ ncnt, int* __restrict__ ecnt,
                               int* __restrict__ nord, int* __restrict__ eord)
{
    const int z = blockIdx.z;
    const int* nidx = z == 0 ? i0 : z == 1 ? i1 : i2;
    const int* eidx = nidx + C_;
    noffs += z * (N_ + 1); eoffs += z * (M_ + 1);
    ncnt += z * N_; ecnt += z * M_; nord += z * C_; eord += z * C_;
    const int c = blockIdx.x * 256 + threadIdx.x;
    const int nd = nidx[c], ed = eidx[c];
    const int p1 = atomicAdd(&ncnt[nd], 1);
    nord[noffs[nd] + p1] = c;
    const int p2 = atomicAdd(&ecnt[ed], 1);
    eord[eoffs[ed] + p2] = c;
}

// s1/s2 from bf16 xp; one wave per (md,b,n)
__global__ __launch_bounds__(64) void hg_s12_kernel(
    const unsigned short* __restrict__ Xp, const float* __restrict__ att,
    float* __restrict__ s1, float* __restrict__ s2)
{
    const int z = blockIdx.z;
    const int bid = blockIdx.x;
    const int b = bid >> 10;
    const int n = bid & (N_ - 1);
    const int lane = threadIdx.x;
    const unsigned short* xr = Xp + (size_t)z * BND_ + (size_t)(b * N_ + n) * D_;
    const ushort4 u = ((const ushort4*)xr)[lane];
    const float4 a1 = ((const float4*)att)[lane];
    const float4 a2 = ((const float4*)(att + D_))[lane];
    float d1 = bf2f(u.x) * a1.x + bf2f(u.y) * a1.y + bf2f(u.z) * a1.z + bf2f(u.w) * a1.w;
    float d2 = bf2f(u.x) * a2.x + bf2f(u.y) * a2.y + bf2f(u.z) * a2.z + bf2f(u.w) * a2.w;
#pragma unroll
    for (int o = 32; o > 0; o >>= 1) { d1 += __shfl_down(d1, o); d2 += __shfl_down(d2, o); }
    if (lane == 0) { s1[z * NB_ + n * 16 + b] = d1; s2[z * NB_ + n * 16 + b] = d2; }
}

__global__ void hg_edge_s2_kernel(const int* __restrict__ i0, const int* __restrict__ i1,
                                  const int* __restrict__ i2,
                                  const float* __restrict__ s2, float* __restrict__ edge_s2)
{
    const int z = blockIdx.z;
    const int* nidx = z == 0 ? i0 : z == 1 ? i1 : i2;
    const int* eidx = nidx + C_;
    const int i = blockIdx.x * 256 + threadIdx.x;   // C*B
    const int c = i >> 4, b = i & 15;
    atomicAdd(&edge_s2[z * M_ * 16 + eidx[c] * 16 + b], s2[z * NB_ + nidx[c] * 16 + b]);
}

__global__ __launch_bounds__(256) void hg_node_softmax_kernel(
    const int* __restrict__ i0, const int* __restrict__ i1, const int* __restrict__ i2,
    const int* __restrict__ noffs, const int* __restrict__ nord,
    const float* __restrict__ s1, const float* __restrict__ edge_s2,
    float* __restrict__ ee, float* __restrict__ inv_sum)
{
    const int z = blockIdx.z;
    const int* eidx = (z == 0 ? i0 : z == 1 ? i1 : i2) + C_;
    noffs += z * (N_ + 1); nord += z * C_;
    s1 += z * NB_; edge_s2 += (size_t)z * M_ * 16;
    ee += (size_t)z * C_ * 16; inv_sum += z * NB_;

    const int n = blockIdx.x;
    const int base = noffs[n];
    const int len = noffs[n + 1] - base;
    if (len == 0) return;
    const int cp = threadIdx.x >> 4;
    const int b = threadIdx.x & 15;
    __shared__ float red[16][16];
    const float s1nb = s1[n * 16 + b];

    float mx = -1e30f;
    for (int i = cp; i < len; i += 16) {
        int c = nord[base + i];
        float e = s1nb + edge_s2[eidx[c] * 16 + b];
        e = e > 0.0f ? e : 0.2f * e;      // leaky_relu 0.2
        mx = fmaxf(mx, e);
    }
    red[cp][b] = mx;
    __syncthreads();
    for (int s = 8; s > 0; s >>= 1) {
        if (cp < s) red[cp][b] = fmaxf(red[cp][b], red[cp + s][b]);
        __syncthreads();
    }
    mx = red[0][b];
    __syncthreads();

    float sm = 0.0f;
    for (int i = cp; i < len; i += 16) {
        int c = nord[base + i];
        float e = s1nb + edge_s2[eidx[c] * 16 + b];
        e = e > 0.0f ? e : 0.2f * e;
        float ex = __expf(e - mx);
        ee[c * 16 + b] = ex;
        sm += ex;
    }
    red[cp][b] = sm;
    __syncthreads();
    for (int s = 8; s > 0; s >>= 1) {
        if (cp < s) red[cp][b] += red[cp + s][b];
        __syncthreads();
    }
    if (cp == 0) inv_sum[n * 16 + b] = 1.0f / (red[0][b] + 1e-16f);
}

// x_edge[m,b,:] — chunk-of-16 MLP restructure (independent loads per chunk)
__global__ __launch_bounds__(256) void hg_xedge_kernel(
    const int* __restrict__ i0, const int* __restrict__ i1, const int* __restrict__ i2,
    const int* __restrict__ eoffs, const int* __restrict__ eord,
    const float* __restrict__ ee, const float* __restrict__ inv_sum,
    const unsigned short* __restrict__ Xp, const float* __restrict__ Bnorm,
    float* __restrict__ x_edge)
{
    const int z = blockIdx.z;
    const int* nidx = z == 0 ? i0 : z == 1 ? i1 : i2;
    eoffs += z * (M_ + 1); eord += z * C_;
    ee += (size_t)z * C_ * 16; inv_sum += z * NB_;
    const unsigned short* xp = Xp + (size_t)z * BND_;
    Bnorm += z * M_; x_edge += (size_t)z * M_ * B_ * D_;

    const int m = blockIdx.x >> 4;
    const int b = blockIdx.x & 15;
    const int d = threadIdx.x;
    const int base = eoffs[m];
    const int len = eoffs[m + 1] - base;
    float acc = 0.0f;
    for (int i0c = 0; i0c < len; i0c += 16) {
        const int cnt = min(16, len - i0c);
        int cc[16], nn[16];
        float cf[16];
#pragma unroll
        for (int j = 0; j < 16; j++) if (j < cnt) cc[j] = eord[base + i0c + j];
#pragma unroll
        for (int j = 0; j < 16; j++) if (j < cnt) nn[j] = nidx[cc[j]];
#pragma unroll
        for (int j = 0; j < 16; j++) if (j < cnt)
            cf[j] = ee[cc[j] * 16 + b] * inv_sum[nn[j] * 16 + b];
#pragma unroll
        for (int j = 0; j < 16; j++) if (j < cnt)
            acc += cf[j] * bf2f(xp[(size_t)(b * N_ + nn[j]) * D_ + d]);
    }
    x_edge[((size_t)(m * 16 + b)) * D_ + d] = Bnorm[m] * acc;
}

// h[b,n,:] — chunk-of-16 MLP restructure
__global__ __launch_bounds__(256) void hg_xnode_kernel(
    const int* __restrict__ i0, const int* __restrict__ i1, const int* __restrict__ i2,
    const int* __restrict__ noffs, const int* __restrict__ nord,
    const float* __restrict__ ee, const float* __restrict__ inv_sum,
    const float* __restrict__ x_edge, const float* __restrict__ Dinv,
    __hip_bfloat16* __restrict__ Hbf)
{
    const int z = blockIdx.z;
    const int* eidx = (z == 0 ? i0 : z == 1 ? i1 : i2) + C_;
    noffs += z * (N_ + 1); nord += z * C_;
    ee += (size_t)z * C_ * 16; inv_sum += z * NB_;
    x_edge += (size_t)z * M_ * B_ * D_; Dinv += z * N_;
    __hip_bfloat16* hbf = Hbf + (size_t)z * BND_;

    const int n = blockIdx.x >> 4;
    const int b = blockIdx.x & 15;
    const int d = threadIdx.x;
    const int base = noffs[n];
    const int len = noffs[n + 1] - base;
    float acc = 0.0f;
    const float inv = (len > 0) ? inv_sum[n * 16 + b] : 0.0f;
    for (int i0c = 0; i0c < len; i0c += 16) {
        const int cnt = min(16, len - i0c);
        int cc[16], em[16];
        float cf[16];
#pragma unroll
        for (int j = 0; j < 16; j++) if (j < cnt) cc[j] = nord[base + i0c + j];
#pragma unroll
        for (int j = 0; j < 16; j++) if (j < cnt) em[j] = eidx[cc[j]];
#pragma unroll
        for (int j = 0; j < 16; j++) if (j < cnt) cf[j] = ee[cc[j] * 16 + b] * inv;
#pragma unroll
        for (int j = 0; j < 16; j++) if (j < cnt)
            acc += cf[j] * x_edge[((size_t)(em[j] * 16 + b)) * D_ + d];
    }
    hbf[((size_t)(b * N_ + n)) * D_ + d] = __float2bfloat16(Dinv[n] * acc);
}

// ---------------------------------------------------------------------------
// Row softmax over bf16 S (1024 cols), rewritten in place as bf16 P.
// ---------------------------------------------------------------------------
__global__ __launch_bounds__(256) void attn_softmax_kernel(unsigned short* __restrict__ S)
{
    unsigned short* p = S + (size_t)blockIdx.x * 1024;
    const int tid = threadIdx.x;
    const int lane = tid & 63, wid = tid >> 6;
    ushort4 u = ((ushort4*)p)[tid];
    const float v0 = bf2f(u.x), v1 = bf2f(u.y), v2 = bf2f(u.z), v3 = bf2f(u.w);
    __shared__ float red[8];

    float m4 = fmaxf(fmaxf(v0, v1), fmaxf(v2, v3));
#pragma unroll
    for (int o = 32; o > 0; o >>= 1) m4 = fmaxf(m4, __shfl_down(m4, o));
    if (lane == 0) red[wid] = m4;
    __syncthreads();
    const float mx = fmaxf(fmaxf(red[0], red[1]), fmaxf(red[2], red[3]));

    const float e0 = __expf(v0 - mx), e1 = __expf(v1 - mx);
    const float e2 = __expf(v2 - mx), e3 = __expf(v3 - mx);
    float s4 = e0 + e1 + e2 + e3;
#pragma unroll
    for (int o = 32; o > 0; o >>= 1) s4 += __shfl_down(s4, o);
    if (lane == 0) red[4 + wid] = s4;
    __syncthreads();
    const float inv = 1.0f / (red[4] + red[5] + red[6] + red[7]);

    u.x = f2bf_bits(e0 * inv);
    u.y = f2bf_bits(e1 * inv);
    u.z = f2bf_bits(e2 * inv);
    u.w = f2bf_bits(e3 * inv);
    ((ushort4*)p)[tid] = u;
}

// ---------------------------------------------------------------------------
// Host
// ---------------------------------------------------------------------------
static inline void launch_gemm(hipStream_t s, dim3 grid,
                               const void* A0, const void* A1, int lda, long long sA,
                               const void* B0, const void* B1, int ldb, long long sB,
                               void* Cv, int ldc, long long sC, long long cOff, long long pieceCs,
                               int K, int kPiece, int zBatches,
                               float scale, const float* bias,
                               const float* a0, const float* a1,
                               const float* a2, const float* a3, int epi)
{
    gemm_nt_kernel<<<grid, 256, 0, s>>>((const __hip_bfloat16*)A0, (const __hip_bfloat16*)A1,
                                        lda, sA,
                                        (const __hip_bfloat16*)B0, (const __hip_bfloat16*)B1,
                                        ldb, sB,
                                        Cv, ldc, sC, cOff, pieceCs, K, kPiece, zBatches,
                                        scale, bias, a0, a1, a2, a3, epi);
}

extern "C" void kernel_launch(void* const* d_in, const int* in_sizes, int n_in,
                              void* d_out, int out_size, void* d_ws, size_t ws_size,
                              hipStream_t stream)
{
    (void)in_sizes; (void)n_in; (void)out_size; (void)ws_size;

    const float* x0 = (const float*)d_in[0];
    const float* x1 = (const float*)d_in[1];
    const float* x2 = (const float*)d_in[2];
    const int* h0 = (const int*)d_in[3];
    const int* h1 = (const int*)d_in[4];
    const int* h2 = (const int*)d_in[5];
    const float* W_hg  = (const float*)d_in[6];
    const float* att_hg= (const float*)d_in[7];
    const float* WQ = (const float*)d_in[8];
    const float* bQ = (const float*)d_in[9];
    const float* WK = (const float*)d_in[10];
    const float* bK = (const float*)d_in[11];
    const float* WV = (const float*)d_in[12];
    const float* bV = (const float*)d_in[13];
    const float* WO = (const float*)d_in[14];
    const float* bO = (const float*)d_in[15];
    float* outp = (float*)d_out;

    char* ws = (char*)d_ws;
    size_t off = 0;
    auto take = [&](size_t bytes) { size_t r = off; off += (bytes + 255) & ~(size_t)255; return r; };

    const size_t oWt   = take((size_t)5 * D_ * D_ * 2);          // 0.63 MB
    const size_t oHbf  = take((size_t)3 * BND_ * 2);             // 24 MB
    const size_t oKall = take((size_t)3 * BND_ * 2);             // 24 MB
    const size_t oVt   = take((size_t)3 * BND_ * 2);             // 24 MB
    const size_t oQb   = take((size_t)BND_ * 2);                 // 8 MB
    const size_t oS    = take((size_t)64 * 1024 * 1024);         // S(2 partners) | Xc+Xp | Vtmp
    const size_t oMsg  = take((size_t)4 * BND_ * 4);             // 64... = 4 pieces x 16MB? no: 4*BND*4 = 64MB? BND*4=16MB -> 4x = 64MB
    const size_t oXe   = take((size_t)3 * M_ * B_ * D_ * 4);     // 6 MB
    const size_t oEE   = take((size_t)3 * C_ * 16 * 4);          // 1.5 MB
    const size_t oS1   = take((size_t)3 * NB_ * 4);
    const size_t oS2   = take((size_t)3 * NB_ * 4);
    const size_t oInv  = take((size_t)3 * NB_ * 4);
    const size_t oZero = take((size_t)3 * (N_ + M_ + M_ * 16) * 4);
    const size_t oNOffs= take((size_t)3 * (N_ + 1) * 4);
    const size_t oEOffs= take((size_t)3 * (M_ + 1) * 4);
    const size_t oNCnt = take((size_t)3 * N_ * 4);
    const size_t oECnt = take((size_t)3 * M_ * 4);
    const size_t oNOrd = take((size_t)3 * C_ * 4);
    const size_t oEOrd = take((size_t)3 * C_ * 4);
    const size_t oDinv = take((size_t)3 * N_ * 4);
    const size_t oBnorm= take((size_t)3 * M_ * 4);

    __hip_bfloat16* Wt   = (__hip_bfloat16*)(ws + oWt);
    __hip_bfloat16* Hbf  = (__hip_bfloat16*)(ws + oHbf);
    __hip_bfloat16* Kall = (__hip_bfloat16*)(ws + oKall);
    __hip_bfloat16* Vt   = (__hip_bfloat16*)(ws + oVt);
    __hip_bfloat16* Qb   = (__hip_bfloat16*)(ws + oQb);
    // oS union: phase1 Xc [0,24MB) + Xp [24,48MB); phase2 Vtmp [0,24MB);
    //           phase3 S = 2 partners x 16 x 1024 x 1024 bf16 = 64 MB
    __hip_bfloat16* Xc   = (__hip_bfloat16*)(ws + oS);
    __hip_bfloat16* Xp   = (__hip_bfloat16*)(ws + oS + (size_t)3 * BND_ * 2);
    __hip_bfloat16* Vtmp = (__hip_bfloat16*)(ws + oS);
    __hip_bfloat16* Sb   = (__hip_bfloat16*)(ws + oS);
    float* Msg  = (float*)(ws + oMsg);
    float* Xe   = (float*)(ws + oXe);
    float* EE   = (float*)(ws + oEE);
    float* S1f  = (float*)(ws + oS1);
    float* S2f  = (float*)(ws + oS2);
    float* Inv  = (float*)(ws + oInv);
    int*   Ddeg = (int*)(ws + oZero);
    int*   Edeg = (int*)(ws + oZero + (size_t)3 * N_ * 4);
    float* Es2  = (float*)(ws + oZero + (size_t)3 * (N_ + M_) * 4);
    const int zeroWords = 3 * (N_ + M_ + M_ * 16);
    int*   NOffs = (int*)(ws + oNOffs);
    int*   EOffs = (int*)(ws + oEOffs);
    int*   NCnt  = (int*)(ws + oNCnt);
    int*   ECnt  = (int*)(ws + oECnt);
    int*   NOrd  = (int*)(ws + oNOrd);
    int*   EOrd  = (int*)(ws + oEOrd);
    float* Dinv  = (float*)(ws + oDinv);
    float* Bnorm = (float*)(ws + oBnorm);

    const int WN = D_ * D_;
    __hip_bfloat16* WtHG = Wt;
    __hip_bfloat16* WtQ  = Wt + (size_t)WN;
    __hip_bfloat16* WtK  = Wt + (size_t)2 * WN;
    __hip_bfloat16* WtV  = Wt + (size_t)3 * WN;
    __hip_bfloat16* WtO  = Wt + (size_t)4 * WN;

    // -------- Phase 0: weights (one dispatch) -------------------------------
    wt_transpose_kernel<<<dim3(8, 8, 5), 256, 0, stream>>>(W_hg, WQ, WK, WV, WO, Wt);

    // -------- Phase 1: hypergraph conv, all modalities batched --------------
    cvt3_kernel<<<dim3((unsigned)(BND_ / 256), 1, 3), 256, 0, stream>>>(x0, x1, x2, Xc);
    zero_kernel<<<(zeroWords + 255) / 256, 256, 0, stream>>>((float*)(ws + oZero), zeroWords);
    hg_count_kernel<<<dim3(C_ / 256, 1, 3), 256, 0, stream>>>(h0, h1, h2, Ddeg, Edeg);
    hg_scan_kernel<<<dim3(1, 1, 3), N_, 0, stream>>>(Ddeg, NOffs, Dinv, NCnt, N_);
    hg_scan_kernel<<<dim3(1, 1, 3), M_, 0, stream>>>(Edeg, EOffs, Bnorm, ECnt, M_);
    hg_fill_kernel<<<dim3(C_ / 256, 1, 3), 256, 0, stream>>>(h0, h1, h2, NOffs, EOffs,
                                                             NCnt, ECnt, NOrd, EOrd);
    // xp = x @ W_hg  -> bf16, z=3
    launch_gemm(stream, dim3(BN_ / 128, D_ / 128, 3),
                Xc, Xc, D_, BND_, WtHG, WtHG, D_, 0,
                Xp, D_, BND_, 0, 0, D_, D_, 3,
                1.0f, nullptr, nullptr, nullptr, nullptr, nullptr, 1);
    hg_s12_kernel<<<dim3(BN_, 1, 3), 64, 0, stream>>>((const unsigned short*)Xp, att_hg, S1f, S2f);
    hg_edge_s2_kernel<<<dim3(C_ * B_ / 256, 1, 3), 256, 0, stream>>>(h0, h1, h2, S2f, Es2);
    hg_node_softmax_kernel<<<dim3(N_, 1, 3), 256, 0, stream>>>(h0, h1, h2, NOffs, NOrd,
                                                               S1f, Es2, EE, Inv);
    hg_xedge_kernel<<<dim3(M_ * B_, 1, 3), 256, 0, stream>>>(h0, h1, h2, EOffs, EOrd, EE, Inv,
                                                             (const unsigned short*)Xp, Bnorm, Xe);
    hg_xnode_kernel<<<dim3(N_ * B_, 1, 3), 256, 0, stream>>>(h0, h1, h2, NOffs, NOrd, EE, Inv,
                                                             Xe, Dinv, Hbf);

    // -------- Phase 2: K, V for all 3 modalities ----------------------------
    launch_gemm(stream, dim3(3 * BN_ / 128, D_ / 128, 1),
                Hbf, Hbf, D_, 0, WtK, WtK, D_, 0,
                Kall, D_, 0, 0, 0, D_, D_, 1,
                1.0f, bK, nullptr, nullptr, nullptr, nullptr, 1);
    launch_gemm(stream, dim3(3 * BN_ / 128, D_ / 128, 1),
                Hbf, Hbf, D_, 0, WtV, WtV, D_, 0,
                Vtmp, D_, 0, 0, 0, D_, D_, 1,
                1.0f, bV, nullptr, nullptr, nullptr, nullptr, 1);
    transpose_bf16_kernel<<<dim3(N_ / 32, D_ / 32, 48), 256, 0, stream>>>(
        Vtmp, Vt, N_, D_, (long long)N_ * D_, (long long)D_ * N_);

    // -------- Phase 3: cross-modal attention + output -----------------------
    const long long NN = (long long)N_ * N_;
    for (int m = 0; m < 3; m++) {
        const __hip_bfloat16* hm = Hbf + (size_t)m * BND_;
        const int pn0 = (m == 0) ? 1 : 0;
        const int pn1 = (m == 2) ? 1 : 2;
        // Q_m
        launch_gemm(stream, dim3(BN_ / 128, D_ / 128, 1),
                    hm, hm, D_, 0, WtQ, WtQ, D_, 0,
                    Qb, D_, 0, 0, 0, D_, D_, 1,
                    1.0f, bQ, nullptr, nullptr, nullptr, nullptr, 1);
        // S for both partners: z = 32 (rem=pi), bf16 out
        launch_gemm(stream, dim3(N_ / 128, N_ / 128, 32),
                    Qb, Qb, D_, (long long)N_ * D_,
                    Kall + (size_t)pn0 * BND_, Kall + (size_t)pn1 * BND_, D_, (long long)N_ * D_,
                    Sb, N_, NN, 0, 16LL * NN, D_, D_, 16,
                    0.0625f, nullptr, nullptr, nullptr, nullptr, nullptr, 1);
        // softmax over all 32768 rows (both partners)
        attn_softmax_kernel<<<2 * B_ * N_, 256, 0, stream>>>((unsigned short*)Sb);
        // PV: z = 64 (rem = pi | kh<<1), split-K=2, 4 Msg pieces fp32
        launch_gemm(stream, dim3(N_ / 128, D_ / 128, 64),
                    Sb, Sb + (size_t)16 * NN, N_, NN,
                    Vt + (size_t)pn0 * BND_, Vt + (size_t)pn1 * BND_, N_, (long long)D_ * N_,
                    Msg, D_, (long long)N_ * D_, 0, BND_, 512, 512, 16,
                    1.0f, nullptr, nullptr, nullptr, nullptr, nullptr, 0);
        // out_m = relu(h_m @ WO + bO + sum of 4 Msg pieces) -> fp32
        launch_gemm(stream, dim3(BN_ / 128, D_ / 128, 1),
                    hm, hm, D_, 0, WtO, WtO, D_, 0,
                    outp, D_, 0, (long long)m * BND_, 0, D_, D_, 1,
                    1.0f, bO, Msg, Msg + BND_, Msg + 2 * BND_, Msg + 3 * BND_, 2);
    }
}

// Round 7
// 1487.480 us; speedup vs baseline: 1.1678x; 1.1678x over previous
//
#include <hip/hip_runtime.h>
#include <hip/hip_bf16.h>
#include <stdint.h>

// ---------------------------------------------------------------------------
// B=16, N=1024, D=256, M=128, C=8192. fp32 in/out, bf16 MFMA internally.
// Output: 3 x [B,N,D] fp32 concatenated.
// ---------------------------------------------------------------------------

namespace {
constexpr int B_ = 16;
constexpr int N_ = 1024;
constexpr int D_ = 256;
constexpr int M_ = 128;
constexpr int C_ = 8192;
constexpr int BN_ = B_ * N_;                       // 16384
constexpr long long BND_ = (long long)BN_ * D_;    // 4,194,304 elems
constexpr int NB_ = N_ * B_;                       // 16384
}

typedef short bf16x8_t __attribute__((ext_vector_type(8)));
typedef float f32x4_t __attribute__((ext_vector_type(4)));

#define DEV static __device__ __forceinline__
DEV float bf2f(unsigned short u) { return __uint_as_float((unsigned)u << 16); }
DEV unsigned short f2bf_bits(float x) { return __builtin_bit_cast(unsigned short, __float2bfloat16(x)); }

// ---------------------------------------------------------------------------
// NT bf16 MFMA GEMM, 128x128 tile, BK=32, 4 waves, software-pipelined staging.
// z decode: batch = z % zBatches; rem = z / zBatches; pi = rem&1 selects the
// (A0,B0)/(A1,B1) pair; kh = rem>>1 gives K-piece offset kh*kPiece.
// Output element: gidx = cOff + rem*pieceCs + batch*sC + row*ldc + col.
// epi: 0 = fp32 C = v            (v = acc*scale)
//      1 = bf16 C = v + bias[col]
//      2 = fp32 C = relu(v + bias[col] + add0..3[idx])   (adds nullable)
// ---------------------------------------------------------------------------
__global__ __launch_bounds__(256) void gemm_nt_kernel(
    const __hip_bfloat16* __restrict__ A0, const __hip_bfloat16* __restrict__ A1,
    int lda, long long sA,
    const __hip_bfloat16* __restrict__ B0, const __hip_bfloat16* __restrict__ B1,
    int ldb, long long sB,
    void* __restrict__ Cv, int ldc, long long sC, long long cOff, long long pieceCs,
    int K, int kPiece, int zBatches,
    float scale, const float* __restrict__ bias,
    const float* __restrict__ add0, const float* __restrict__ add1,
    const float* __restrict__ add2, const float* __restrict__ add3,
    int epi)
{
    __shared__ __align__(16) short smA[128 * 32];
    __shared__ __align__(16) short smB[128 * 32];

    const int tid = threadIdx.x;
    const int wid = tid >> 6;
    const int lane = tid & 63;
    const int z = blockIdx.z;
    const int batch = z % zBatches;
    const int rem = z / zBatches;
    const int pi = rem & 1;
    const int kh = rem >> 1;

    const short* Ab = (const short*)(pi ? A1 : A0) + (size_t)batch * sA
                    + (size_t)blockIdx.x * 128 * lda + (size_t)kh * kPiece;
    const short* Bb = (const short*)(pi ? B1 : B0) + (size_t)batch * sB
                    + (size_t)blockIdx.y * 128 * ldb + (size_t)kh * kPiece;

    const int wm = (wid >> 1) * 64;
    const int wn = (wid & 1) * 64;
    const int fr = lane & 15;            // fragment row (m or n)
    const int kq = (lane >> 4) * 8;      // k-offset of this lane's 8 elems
    const int sr = tid >> 2;             // staging row 0..63 (plus h*64)
    const int sc = (tid & 3) * 8;        // staging short-col

    f32x4_t acc[4][4] = {};
    int4 avv[2], bvv[2];
#pragma unroll
    for (int h = 0; h < 2; h++) {        // prologue: tile 0
        const int row = h * 64 + sr;
        avv[h] = *(const int4*)(Ab + (size_t)row * lda + sc);
        bvv[h] = *(const int4*)(Bb + (size_t)row * ldb + sc);
    }

    for (int k0 = 0; k0 < K; k0 += 32) {
        __syncthreads();                 // prior tile's ds_reads complete
#pragma unroll
        for (int h = 0; h < 2; h++) {
            const int row = h * 64 + sr;
            *(int4*)&smA[row * 32 + sc] = avv[h];
            *(int4*)&smB[row * 32 + sc] = bvv[h];
        }
        __syncthreads();

        const int kn = k0 + 32;          // prefetch next tile (overlaps MFMA)
        if (kn < K) {
#pragma unroll
            for (int h = 0; h < 2; h++) {
                const int row = h * 64 + sr;
                avv[h] = *(const int4*)(Ab + (size_t)row * lda + (kn + sc));
                bvv[h] = *(const int4*)(Bb + (size_t)row * ldb + (kn + sc));
            }
        }

        bf16x8_t af[4], bfv[4];
#pragma unroll
        for (int i = 0; i < 4; i++)
            af[i] = *(const bf16x8_t*)&smA[(wm + i * 16 + fr) * 32 + kq];
#pragma unroll
        for (int j = 0; j < 4; j++)
            bfv[j] = *(const bf16x8_t*)&smB[(wn + j * 16 + fr) * 32 + kq];
#pragma unroll
        for (int i = 0; i < 4; i++)
#pragma unroll
            for (int j = 0; j < 4; j++)
                acc[i][j] = __builtin_amdgcn_mfma_f32_16x16x32_bf16(af[i], bfv[j], acc[i][j], 0, 0, 0);
    }

    const int rb = (lane >> 4) * 4;
#pragma unroll
    for (int j = 0; j < 4; j++) {
        const int col = blockIdx.y * 128 + wn + j * 16 + fr;
        const float bv = bias ? bias[col] : 0.0f;
#pragma unroll
        for (int i = 0; i < 4; i++) {
#pragma unroll
            for (int r = 0; r < 4; r++) {
                const int row = blockIdx.x * 128 + wm + i * 16 + rb + r;
                const size_t idx = (size_t)batch * sC + (size_t)row * ldc + col;
                const size_t gidx = (size_t)cOff + (size_t)rem * pieceCs + idx;
                const float v = acc[i][j][r] * scale;
                if (epi == 0) {
                    ((float*)Cv)[gidx] = v;
                } else if (epi == 1) {
                    ((__hip_bfloat16*)Cv)[gidx] = __float2bfloat16(v + bv);
                } else {
                    float o = v + bv;
                    if (add0) o += add0[idx];
                    if (add1) o += add1[idx];
                    if (add2) o += add2[idx];
                    if (add3) o += add3[idx];
                    ((float*)Cv)[gidx] = o > 0.0f ? o : 0.0f;
                }
            }
        }
    }
}

// ---------------------------------------------------------------------------
// Weight convert+transpose, all 5 weights in one dispatch (z selects).
// ---------------------------------------------------------------------------
__global__ __launch_bounds__(256) void wt_transpose_kernel(
    const float* __restrict__ W0, const float* __restrict__ W1,
    const float* __restrict__ W2, const float* __restrict__ W3,
    const float* __restrict__ W4, __hip_bfloat16* __restrict__ out)
{
    const int z = blockIdx.z;
    const float* in = z == 0 ? W0 : z == 1 ? W1 : z == 2 ? W2 : z == 3 ? W3 : W4;
    __hip_bfloat16* o = out + (size_t)z * D_ * D_;
    __shared__ float t[32][33];
    const int r0 = blockIdx.x * 32, c0 = blockIdx.y * 32;
    const int tx = threadIdx.x & 31, ty = threadIdx.x >> 5;
#pragma unroll
    for (int k = 0; k < 4; k++) {
        int r = ty + k * 8;
        t[r][tx] = in[(size_t)(r0 + r) * D_ + (c0 + tx)];
    }
    __syncthreads();
#pragma unroll
    for (int k = 0; k < 4; k++) {
        int r = ty + k * 8;
        o[(size_t)(c0 + r) * D_ + (r0 + tx)] = __float2bfloat16(t[tx][r]);
    }
}

// bf16 transpose for V: out[c][r] = in[r][c], batched over z.
__global__ __launch_bounds__(256) void transpose_bf16_kernel(
    const __hip_bfloat16* __restrict__ in, __hip_bfloat16* __restrict__ out,
    int R, int Cc, long long sIn, long long sOut)
{
    __shared__ short t[32][33];
    const size_t bz = blockIdx.z;
    const short* I = (const short*)in + bz * (size_t)sIn;
    short* O = (short*)out + bz * (size_t)sOut;
    const int r0 = blockIdx.x * 32, c0 = blockIdx.y * 32;
    const int tx = threadIdx.x & 31, ty = threadIdx.x >> 5;
#pragma unroll
    for (int k = 0; k < 4; k++) {
        int r = ty + k * 8;
        t[r][tx] = I[(size_t)(r0 + r) * Cc + (c0 + tx)];
    }
    __syncthreads();
#pragma unroll
    for (int k = 0; k < 4; k++) {
        int r = ty + k * 8;
        O[(size_t)(c0 + r) * R + (r0 + tx)] = t[tx][r];
    }
}

// all 3 modality inputs fp32 -> bf16, one dispatch
__global__ void cvt3_kernel(const float* __restrict__ x0, const float* __restrict__ x1,
                            const float* __restrict__ x2, __hip_bfloat16* __restrict__ dst)
{
    const int z = blockIdx.z;
    const float* s = z == 0 ? x0 : z == 1 ? x1 : x2;
    const long long i = (long long)blockIdx.x * 256 + threadIdx.x;
    dst[(size_t)z * BND_ + i] = __float2bfloat16(s[i]);
}

__global__ void zero_kernel(float* __restrict__ p, int n)
{
    const int i = blockIdx.x * 256 + threadIdx.x;
    if (i < n) p[i] = 0.0f;
}

// ---------------------------------------------------------------------------
// Hypergraph pipeline, batched over 3 modalities via blockIdx.z
// ---------------------------------------------------------------------------
__global__ void hg_count_kernel(const int* __restrict__ i0, const int* __restrict__ i1,
                                const int* __restrict__ i2,
                                int* __restrict__ Ddeg, int* __restrict__ Edeg)
{
    const int z = blockIdx.z;
    const int* idx = z == 0 ? i0 : z == 1 ? i1 : i2;
    const int c = blockIdx.x * 256 + threadIdx.x;
    atomicAdd(&Ddeg[z * N_ + idx[c]], 1);
    atomicAdd(&Edeg[z * M_ + idx[C_ + c]], 1);
}

__global__ __launch_bounds__(1024) void hg_scan_kernel(
    const int* __restrict__ deg, int* __restrict__ offs,
    float* __restrict__ inv, int* __restrict__ cnt, int len)
{
    const int z = blockIdx.z;
    deg += z * len; offs += z * (len + 1); inv += z * len; cnt += z * len;
    __shared__ int tmp[1024];
    const int t = threadIdx.x;
    const int v = deg[t];
    tmp[t] = v;
    __syncthreads();
    for (int o = 1; o < len; o <<= 1) {
        int x = (t >= o) ? tmp[t - o] : 0;
        __syncthreads();
        tmp[t] += x;
        __syncthreads();
    }
    offs[t] = tmp[t] - v;
    if (t == len - 1) offs[len] = tmp[t];
    inv[t] = (v > 0) ? (1.0f / (float)v) : 0.0f;
    cnt[t] = 0;
}

__global__ void hg_fill_kernel(const int* __restrict__ i0, const int* __restrict__ i1,
                               const int* __restrict__ i2,
                               const int* __restrict__ noffs, const int* __restrict__ eoffs,
                               int* __restrict__ ncnt, int* __restrict__ ecnt,
                               int* __restrict__ nord, int* __restrict__ eord)
{
    const int z = blockIdx.z;
    const int* nidx = z == 0 ? i0 : z == 1 ? i1 : i2;
    const int* eidx = nidx + C_;
    noffs += z * (N_ + 1); eoffs += z * (M_ + 1);
    ncnt += z * N_; ecnt += z * M_; nord += z * C_; eord += z * C_;
    const int c = blockIdx.x * 256 + threadIdx.x;
    const int nd = nidx[c], ed = eidx[c];
    const int p1 = atomicAdd(&ncnt[nd], 1);
    nord[noffs[nd] + p1] = c;
    const int p2 = atomicAdd(&ecnt[ed], 1);
    eord[eoffs[ed] + p2] = c;
}

// s1/s2 from bf16 xp; one wave per (md,b,n)
__global__ __launch_bounds__(64) void hg_s12_kernel(
    const unsigned short* __restrict__ Xp, const float* __restrict__ att,
    float* __restrict__ s1, float* __restrict__ s2)
{
    const int z = blockIdx.z;
    const int bid = blockIdx.x;
    const int b = bid >> 10;
    const int n = bid & (N_ - 1);
    const int lane = threadIdx.x;
    const unsigned short* xr = Xp + (size_t)z * BND_ + (size_t)(b * N_ + n) * D_;
    const ushort4 u = ((const ushort4*)xr)[lane];
    const float4 a1 = ((const float4*)att)[lane];
    const float4 a2 = ((const float4*)(att + D_))[lane];
    float d1 = bf2f(u.x) * a1.x + bf2f(u.y) * a1.y + bf2f(u.z) * a1.z + bf2f(u.w) * a1.w;
    float d2 = bf2f(u.x) * a2.x + bf2f(u.y) * a2.y + bf2f(u.z) * a2.z + bf2f(u.w) * a2.w;
#pragma unroll
    for (int o = 32; o > 0; o >>= 1) { d1 += __shfl_down(d1, o); d2 += __shfl_down(d2, o); }
    if (lane == 0) { s1[z * NB_ + n * 16 + b] = d1; s2[z * NB_ + n * 16 + b] = d2; }
}

// edge_s2[m,b] = sum over edge m's incidences of s2[node,b]  (atomic-free)
// grid (M_, 1, 3), 256 thr = 16 pos x 16 b, LDS reduce over pos.
__global__ __launch_bounds__(256) void hg_edge_s2_kernel(
    const int* __restrict__ i0, const int* __restrict__ i1, const int* __restrict__ i2,
    const int* __restrict__ eoffs, const int* __restrict__ eord,
    const float* __restrict__ s2, float* __restrict__ edge_s2)
{
    const int z = blockIdx.z;
    const int* nidx = z == 0 ? i0 : z == 1 ? i1 : i2;
    eoffs += z * (M_ + 1); eord += z * C_;
    s2 += z * NB_; edge_s2 += (size_t)z * M_ * 16;

    const int m = blockIdx.x;
    const int pos = threadIdx.x >> 4;
    const int b = threadIdx.x & 15;
    const int base = eoffs[m];
    const int len = eoffs[m + 1] - base;
    float acc = 0.0f;
#pragma unroll 4
    for (int i = pos; i < len; i += 16) {
        int c = eord[base + i];
        acc += s2[nidx[c] * 16 + b];
    }
    __shared__ float red[16][16];
    red[pos][b] = acc;
    __syncthreads();
    for (int s = 8; s > 0; s >>= 1) {
        if (pos < s) red[pos][b] += red[pos + s][b];
        __syncthreads();
    }
    if (pos == 0) edge_s2[m * 16 + b] = red[0][b];
}

__global__ __launch_bounds__(256) void hg_node_softmax_kernel(
    const int* __restrict__ i0, const int* __restrict__ i1, const int* __restrict__ i2,
    const int* __restrict__ noffs, const int* __restrict__ nord,
    const float* __restrict__ s1, const float* __restrict__ edge_s2,
    float* __restrict__ ee, float* __restrict__ inv_sum)
{
    const int z = blockIdx.z;
    const int* eidx = (z == 0 ? i0 : z == 1 ? i1 : i2) + C_;
    noffs += z * (N_ + 1); nord += z * C_;
    s1 += z * NB_; edge_s2 += (size_t)z * M_ * 16;
    ee += (size_t)z * C_ * 16; inv_sum += z * NB_;

    const int n = blockIdx.x;
    const int base = noffs[n];
    const int len = noffs[n + 1] - base;
    if (len == 0) return;
    const int cp = threadIdx.x >> 4;
    const int b = threadIdx.x & 15;
    __shared__ float red[16][16];
    const float s1nb = s1[n * 16 + b];

    float mx = -1e30f;
    for (int i = cp; i < len; i += 16) {
        int c = nord[base + i];
        float e = s1nb + edge_s2[eidx[c] * 16 + b];
        e = e > 0.0f ? e : 0.2f * e;      // leaky_relu 0.2
        mx = fmaxf(mx, e);
    }
    red[cp][b] = mx;
    __syncthreads();
    for (int s = 8; s > 0; s >>= 1) {
        if (cp < s) red[cp][b] = fmaxf(red[cp][b], red[cp + s][b]);
        __syncthreads();
    }
    mx = red[0][b];
    __syncthreads();

    float sm = 0.0f;
    for (int i = cp; i < len; i += 16) {
        int c = nord[base + i];
        float e = s1nb + edge_s2[eidx[c] * 16 + b];
        e = e > 0.0f ? e : 0.2f * e;
        float ex = __expf(e - mx);
        ee[c * 16 + b] = ex;
        sm += ex;
    }
    red[cp][b] = sm;
    __syncthreads();
    for (int s = 8; s > 0; s >>= 1) {
        if (cp < s) red[cp][b] += red[cp + s][b];
        __syncthreads();
    }
    if (cp == 0) inv_sum[n * 16 + b] = 1.0f / (red[0][b] + 1e-16f);
}

// Pack sorted-order gather arrays: kills the 3-deep dependent chain in
// xedge/xnode.  EmS[i]=eidx[nord[i]], CoefN[i,b]=alpha for node-order pos i;
// NnS[i]=nidx[eord[i]], CoefE[i,b]=alpha for edge-order pos i.
__global__ __launch_bounds__(256) void hg_pack_kernel(
    const int* __restrict__ i0, const int* __restrict__ i1, const int* __restrict__ i2,
    const int* __restrict__ nord, const int* __restrict__ eord,
    const float* __restrict__ ee, const float* __restrict__ inv_sum,
    int* __restrict__ EmS, int* __restrict__ NnS,
    float* __restrict__ CoefN, float* __restrict__ CoefE)
{
    const int z = blockIdx.z;
    const int* nidx = z == 0 ? i0 : z == 1 ? i1 : i2;
    const int* eidx = nidx + C_;
    nord += z * C_; eord += z * C_;
    ee += (size_t)z * C_ * 16; inv_sum += z * NB_;
    EmS += z * C_; NnS += z * C_;
    CoefN += (size_t)z * C_ * 16; CoefE += (size_t)z * C_ * 16;

    const int gid = blockIdx.x * 256 + threadIdx.x;   // C*16
    const int i = gid >> 4, b = gid & 15;
    const int c1 = nord[i], c2 = eord[i];
    const int n1 = nidx[c1], n2 = nidx[c2];
    if (b == 0) { EmS[i] = eidx[c1]; NnS[i] = n2; }
    CoefN[i * 16 + b] = ee[c1 * 16 + b] * inv_sum[n1 * 16 + b];
    CoefE[i * 16 + b] = ee[c2 * 16 + b] * inv_sum[n2 * 16 + b];
}

// x_edge[m,b,:] via packed arrays: 2-deep chain, independent iterations.
__global__ __launch_bounds__(256) void hg_xedge_kernel(
    const int* __restrict__ eoffs, const int* __restrict__ NnS,
    const float* __restrict__ CoefE, const unsigned short* __restrict__ Xp,
    const float* __restrict__ Bnorm, float* __restrict__ x_edge)
{
    const int z = blockIdx.z;
    eoffs += z * (M_ + 1); NnS += z * C_;
    CoefE += (size_t)z * C_ * 16;
    const unsigned short* xp = Xp + (size_t)z * BND_;
    Bnorm += z * M_; x_edge += (size_t)z * M_ * B_ * D_;

    const int m = blockIdx.x >> 4;
    const int b = blockIdx.x & 15;
    const int d = threadIdx.x;
    const int base = eoffs[m];
    const int len = eoffs[m + 1] - base;
    float acc = 0.0f;
#pragma unroll 4
    for (int i = 0; i < len; i++) {
        const int nn = NnS[base + i];
        const float cf = CoefE[(size_t)(base + i) * 16 + b];
        acc += cf * bf2f(xp[(size_t)(b * N_ + nn) * D_ + d]);
    }
    x_edge[((size_t)(m * 16 + b)) * D_ + d] = Bnorm[m] * acc;
}

// h[b,n,:] via packed arrays.
__global__ __launch_bounds__(256) void hg_xnode_kernel(
    const int* __restrict__ noffs, const int* __restrict__ EmS,
    const float* __restrict__ CoefN, const float* __restrict__ x_edge,
    const float* __restrict__ Dinv, __hip_bfloat16* __restrict__ Hbf)
{
    const int z = blockIdx.z;
    noffs += z * (N_ + 1); EmS += z * C_;
    CoefN += (size_t)z * C_ * 16;
    x_edge += (size_t)z * M_ * B_ * D_; Dinv += z * N_;
    __hip_bfloat16* hbf = Hbf + (size_t)z * BND_;

    const int n = blockIdx.x >> 4;
    const int b = blockIdx.x & 15;
    const int d = threadIdx.x;
    const int base = noffs[n];
    const int len = noffs[n + 1] - base;
    float acc = 0.0f;
#pragma unroll 4
    for (int i = 0; i < len; i++) {
        const int em = EmS[base + i];
        const float cf = CoefN[(size_t)(base + i) * 16 + b];
        acc += cf * x_edge[((size_t)(em * 16 + b)) * D_ + d];
    }
    hbf[((size_t)(b * N_ + n)) * D_ + d] = __float2bfloat16(Dinv[n] * acc);
}

// ---------------------------------------------------------------------------
// Row softmax over bf16 S (1024 cols), rewritten in place as bf16 P.
// ---------------------------------------------------------------------------
__global__ __launch_bounds__(256) void attn_softmax_kernel(unsigned short* __restrict__ S)
{
    unsigned short* p = S + (size_t)blockIdx.x * 1024;
    const int tid = threadIdx.x;
    const int lane = tid & 63, wid = tid >> 6;
    ushort4 u = ((ushort4*)p)[tid];
    const float v0 = bf2f(u.x), v1 = bf2f(u.y), v2 = bf2f(u.z), v3 = bf2f(u.w);
    __shared__ float red[8];

    float m4 = fmaxf(fmaxf(v0, v1), fmaxf(v2, v3));
#pragma unroll
    for (int o = 32; o > 0; o >>= 1) m4 = fmaxf(m4, __shfl_down(m4, o));
    if (lane == 0) red[wid] = m4;
    __syncthreads();
    const float mx = fmaxf(fmaxf(red[0], red[1]), fmaxf(red[2], red[3]));

    const float e0 = __expf(v0 - mx), e1 = __expf(v1 - mx);
    const float e2 = __expf(v2 - mx), e3 = __expf(v3 - mx);
    float s4 = e0 + e1 + e2 + e3;
#pragma unroll
    for (int o = 32; o > 0; o >>= 1) s4 += __shfl_down(s4, o);
    if (lane == 0) red[4 + wid] = s4;
    __syncthreads();
    const float inv = 1.0f / (red[4] + red[5] + red[6] + red[7]);

    u.x = f2bf_bits(e0 * inv);
    u.y = f2bf_bits(e1 * inv);
    u.z = f2bf_bits(e2 * inv);
    u.w = f2bf_bits(e3 * inv);
    ((ushort4*)p)[tid] = u;
}

// ---------------------------------------------------------------------------
// Host
// ---------------------------------------------------------------------------
static inline void launch_gemm(hipStream_t s, dim3 grid,
                               const void* A0, const void* A1, int lda, long long sA,
                               const void* B0, const void* B1, int ldb, long long sB,
                               void* Cv, int ldc, long long sC, long long cOff, long long pieceCs,
                               int K, int kPiece, int zBatches,
                               float scale, const float* bias,
                               const float* a0, const float* a1,
                               const float* a2, const float* a3, int epi)
{
    gemm_nt_kernel<<<grid, 256, 0, s>>>((const __hip_bfloat16*)A0, (const __hip_bfloat16*)A1,
                                        lda, sA,
                                        (const __hip_bfloat16*)B0, (const __hip_bfloat16*)B1,
                                        ldb, sB,
                                        Cv, ldc, sC, cOff, pieceCs, K, kPiece, zBatches,
                                        scale, bias, a0, a1, a2, a3, epi);
}

extern "C" void kernel_launch(void* const* d_in, const int* in_sizes, int n_in,
                              void* d_out, int out_size, void* d_ws, size_t ws_size,
                              hipStream_t stream)
{
    (void)in_sizes; (void)n_in; (void)out_size; (void)ws_size;

    const float* x0 = (const float*)d_in[0];
    const float* x1 = (const float*)d_in[1];
    const float* x2 = (const float*)d_in[2];
    const int* h0 = (const int*)d_in[3];
    const int* h1 = (const int*)d_in[4];
    const int* h2 = (const int*)d_in[5];
    const float* W_hg  = (const float*)d_in[6];
    const float* att_hg= (const float*)d_in[7];
    const float* WQ = (const float*)d_in[8];
    const float* bQ = (const float*)d_in[9];
    const float* WK = (const float*)d_in[10];
    const float* bK = (const float*)d_in[11];
    const float* WV = (const float*)d_in[12];
    const float* bV = (const float*)d_in[13];
    const float* WO = (const float*)d_in[14];
    const float* bO = (const float*)d_in[15];
    float* outp = (float*)d_out;

    char* ws = (char*)d_ws;
    size_t off = 0;
    auto take = [&](size_t bytes) { size_t r = off; off += (bytes + 255) & ~(size_t)255; return r; };

    const size_t oWt   = take((size_t)5 * D_ * D_ * 2);          // 0.63 MB
    const size_t oHbf  = take((size_t)3 * BND_ * 2);             // 24 MB
    const size_t oKall = take((size_t)3 * BND_ * 2);             // 24 MB
    const size_t oVt   = take((size_t)3 * BND_ * 2);             // 24 MB
    const size_t oQb   = take((size_t)BND_ * 2);                 // 8 MB
    const size_t oS    = take((size_t)64 * 1024 * 1024);         // S(2 partners) | Xc+Xp | Vtmp
    const size_t oMsg  = take((size_t)4 * BND_ * 4);             // 64 MB (4 PV pieces)
    const size_t oXe   = take((size_t)3 * M_ * B_ * D_ * 4);     // 6 MB
    const size_t oEE   = take((size_t)3 * C_ * 16 * 4);          // 1.5 MB
    const size_t oCoefN= take((size_t)3 * C_ * 16 * 4);          // 1.5 MB
    const size_t oCoefE= take((size_t)3 * C_ * 16 * 4);          // 1.5 MB
    const size_t oEmS  = take((size_t)3 * C_ * 4);
    const size_t oNnS  = take((size_t)3 * C_ * 4);
    const size_t oS1   = take((size_t)3 * NB_ * 4);
    const size_t oS2   = take((size_t)3 * NB_ * 4);
    const size_t oInv  = take((size_t)3 * NB_ * 4);
    const size_t oZero = take((size_t)3 * (N_ + M_) * 4);        // Ddeg|Edeg only
    const size_t oEs2  = take((size_t)3 * M_ * 16 * 4);
    const size_t oNOffs= take((size_t)3 * (N_ + 1) * 4);
    const size_t oEOffs= take((size_t)3 * (M_ + 1) * 4);
    const size_t oNCnt = take((size_t)3 * N_ * 4);
    const size_t oECnt = take((size_t)3 * M_ * 4);
    const size_t oNOrd = take((size_t)3 * C_ * 4);
    const size_t oEOrd = take((size_t)3 * C_ * 4);
    const size_t oDinv = take((size_t)3 * N_ * 4);
    const size_t oBnorm= take((size_t)3 * M_ * 4);

    __hip_bfloat16* Wt   = (__hip_bfloat16*)(ws + oWt);
    __hip_bfloat16* Hbf  = (__hip_bfloat16*)(ws + oHbf);
    __hip_bfloat16* Kall = (__hip_bfloat16*)(ws + oKall);
    __hip_bfloat16* Vt   = (__hip_bfloat16*)(ws + oVt);
    __hip_bfloat16* Qb   = (__hip_bfloat16*)(ws + oQb);
    // oS union: phase1 Xc [0,24MB) + Xp [24,48MB); phase2 Vtmp [0,24MB);
    //           phase3 S = 2 partners x 16 x 1024 x 1024 bf16 = 64 MB
    __hip_bfloat16* Xc   = (__hip_bfloat16*)(ws + oS);
    __hip_bfloat16* Xp   = (__hip_bfloat16*)(ws + oS + (size_t)3 * BND_ * 2);
    __hip_bfloat16* Vtmp = (__hip_bfloat16*)(ws + oS);
    __hip_bfloat16* Sb   = (__hip_bfloat16*)(ws + oS);
    float* Msg  = (float*)(ws + oMsg);
    float* Xe   = (float*)(ws + oXe);
    float* EE   = (float*)(ws + oEE);
    float* CoefN= (float*)(ws + oCoefN);
    float* CoefE= (float*)(ws + oCoefE);
    int*   EmS  = (int*)(ws + oEmS);
    int*   NnS  = (int*)(ws + oNnS);
    float* S1f  = (float*)(ws + oS1);
    float* S2f  = (float*)(ws + oS2);
    float* Inv  = (float*)(ws + oInv);
    int*   Ddeg = (int*)(ws + oZero);
    int*   Edeg = (int*)(ws + oZero + (size_t)3 * N_ * 4);
    float* Es2  = (float*)(ws + oEs2);
    const int zeroWords = 3 * (N_ + M_);
    int*   NOffs = (int*)(ws + oNOffs);
    int*   EOffs = (int*)(ws + oEOffs);
    int*   NCnt  = (int*)(ws + oNCnt);
    int*   ECnt  = (int*)(ws + oECnt);
    int*   NOrd  = (int*)(ws + oNOrd);
    int*   EOrd  = (int*)(ws + oEOrd);
    float* Dinv  = (float*)(ws + oDinv);
    float* Bnorm = (float*)(ws + oBnorm);

    const int WN = D_ * D_;
    __hip_bfloat16* WtHG = Wt;
    __hip_bfloat16* WtQ  = Wt + (size_t)WN;
    __hip_bfloat16* WtK  = Wt + (size_t)2 * WN;
    __hip_bfloat16* WtV  = Wt + (size_t)3 * WN;
    __hip_bfloat16* WtO  = Wt + (size_t)4 * WN;

    // -------- Phase 0: weights (one dispatch) -------------------------------
    wt_transpose_kernel<<<dim3(8, 8, 5), 256, 0, stream>>>(W_hg, WQ, WK, WV, WO, Wt);

    // -------- Phase 1: hypergraph conv, all modalities batched --------------
    cvt3_kernel<<<dim3((unsigned)(BND_ / 256), 1, 3), 256, 0, stream>>>(x0, x1, x2, Xc);
    zero_kernel<<<(zeroWords + 255) / 256, 256, 0, stream>>>((float*)(ws + oZero), zeroWords);
    hg_count_kernel<<<dim3(C_ / 256, 1, 3), 256, 0, stream>>>(h0, h1, h2, Ddeg, Edeg);
    hg_scan_kernel<<<dim3(1, 1, 3), N_, 0, stream>>>(Ddeg, NOffs, Dinv, NCnt, N_);
    hg_scan_kernel<<<dim3(1, 1, 3), M_, 0, stream>>>(Edeg, EOffs, Bnorm, ECnt, M_);
    hg_fill_kernel<<<dim3(C_ / 256, 1, 3), 256, 0, stream>>>(h0, h1, h2, NOffs, EOffs,
                                                             NCnt, ECnt, NOrd, EOrd);
    // xp = x @ W_hg  -> bf16, z=3
    launch_gemm(stream, dim3(BN_ / 128, D_ / 128, 3),
                Xc, Xc, D_, BND_, WtHG, WtHG, D_, 0,
                Xp, D_, BND_, 0, 0, D_, D_, 3,
                1.0f, nullptr, nullptr, nullptr, nullptr, nullptr, 1);
    hg_s12_kernel<<<dim3(BN_, 1, 3), 64, 0, stream>>>((const unsigned short*)Xp, att_hg, S1f, S2f);
    hg_edge_s2_kernel<<<dim3(M_, 1, 3), 256, 0, stream>>>(h0, h1, h2, EOffs, EOrd, S2f, Es2);
    hg_node_softmax_kernel<<<dim3(N_, 1, 3), 256, 0, stream>>>(h0, h1, h2, NOffs, NOrd,
                                                               S1f, Es2, EE, Inv);
    hg_pack_kernel<<<dim3(C_ * 16 / 256, 1, 3), 256, 0, stream>>>(h0, h1, h2, NOrd, EOrd,
                                                                  EE, Inv, EmS, NnS, CoefN, CoefE);
    hg_xedge_kernel<<<dim3(M_ * B_, 1, 3), 256, 0, stream>>>(EOffs, NnS, CoefE,
                                                             (const unsigned short*)Xp, Bnorm, Xe);
    hg_xnode_kernel<<<dim3(N_ * B_, 1, 3), 256, 0, stream>>>(NOffs, EmS, CoefN, Xe, Dinv, Hbf);

    // -------- Phase 2: K, V for all 3 modalities ----------------------------
    launch_gemm(stream, dim3(3 * BN_ / 128, D_ / 128, 1),
                Hbf, Hbf, D_, 0, WtK, WtK, D_, 0,
                Kall, D_, 0, 0, 0, D_, D_, 1,
                1.0f, bK, nullptr, nullptr, nullptr, nullptr, 1);
    launch_gemm(stream, dim3(3 * BN_ / 128, D_ / 128, 1),
                Hbf, Hbf, D_, 0, WtV, WtV, D_, 0,
                Vtmp, D_, 0, 0, 0, D_, D_, 1,
                1.0f, bV, nullptr, nullptr, nullptr, nullptr, 1);
    transpose_bf16_kernel<<<dim3(N_ / 32, D_ / 32, 48), 256, 0, stream>>>(
        Vtmp, Vt, N_, D_, (long long)N_ * D_, (long long)D_ * N_);

    // -------- Phase 3: cross-modal attention + output -----------------------
    const long long NN = (long long)N_ * N_;
    for (int m = 0; m < 3; m++) {
        const __hip_bfloat16* hm = Hbf + (size_t)m * BND_;
        const int pn0 = (m == 0) ? 1 : 0;
        const int pn1 = (m == 2) ? 1 : 2;
        // Q_m
        launch_gemm(stream, dim3(BN_ / 128, D_ / 128, 1),
                    hm, hm, D_, 0, WtQ, WtQ, D_, 0,
                    Qb, D_, 0, 0, 0, D_, D_, 1,
                    1.0f, bQ, nullptr, nullptr, nullptr, nullptr, 1);
        // S for both partners: z = 32 (rem=pi), bf16 out
        launch_gemm(stream, dim3(N_ / 128, N_ / 128, 32),
                    Qb, Qb, D_, (long long)N_ * D_,
                    Kall + (size_t)pn0 * BND_, Kall + (size_t)pn1 * BND_, D_, (long long)N_ * D_,
                    Sb, N_, NN, 0, 16LL * NN, D_, D_, 16,
                    0.0625f, nullptr, nullptr, nullptr, nullptr, nullptr, 1);
        // softmax over all 32768 rows (both partners)
        attn_softmax_kernel<<<2 * B_ * N_, 256, 0, stream>>>((unsigned short*)Sb);
        // PV: z = 64 (rem = pi | kh<<1), split-K=2, 4 Msg pieces fp32
        launch_gemm(stream, dim3(N_ / 128, D_ / 128, 64),
                    Sb, Sb + (size_t)16 * NN, N_, NN,
                    Vt + (size_t)pn0 * BND_, Vt + (size_t)pn1 * BND_, N_, (long long)D_ * N_,
                    Msg, D_, (long long)N_ * D_, 0, BND_, 512, 512, 16,
                    1.0f, nullptr, nullptr, nullptr, nullptr, nullptr, 0);
        // out_m = relu(h_m @ WO + bO + sum of 4 Msg pieces) -> fp32
        launch_gemm(stream, dim3(BN_ / 128, D_ / 128, 1),
                    hm, hm, D_, 0, WtO, WtO, D_, 0,
                    outp, D_, 0, (long long)m * BND_, 0, D_, D_, 1,
                    1.0f, bO, Msg, Msg + BND_, Msg + 2 * BND_, Msg + 3 * BND_, 2);
    }
}

// Round 8
// 1168.856 us; speedup vs baseline: 1.4861x; 1.2726x over previous
//
#include <hip/hip_runtime.h>
#include <hip/hip_bf16.h>
#include <stdint.h>

// ---------------------------------------------------------------------------
// B=16, N=1024, D=256, M=128, C=8192. fp32 in/out, bf16 MFMA internally.
// Output: 3 x [B,N,D] fp32 concatenated.
// ---------------------------------------------------------------------------

namespace {
constexpr int B_ = 16;
constexpr int N_ = 1024;
constexpr int D_ = 256;
constexpr int M_ = 128;
constexpr int C_ = 8192;
constexpr int BN_ = B_ * N_;                       // 16384
constexpr long long BND_ = (long long)BN_ * D_;    // 4,194,304 elems
constexpr int NB_ = N_ * B_;                       // 16384
constexpr int LDA_S = 40;                          // K-loop LDS stride (shorts), breaks bank conflicts
constexpr int EPI_S = 68;                          // epilogue LDS stride (floats), 16B-aligned rows
}

typedef short bf16x8_t __attribute__((ext_vector_type(8)));
typedef float f32x4_t __attribute__((ext_vector_type(4)));
typedef unsigned short u16x8_t __attribute__((ext_vector_type(8)));

#define DEV static __device__ __forceinline__
DEV float bf2f(unsigned short u) { return __uint_as_float((unsigned)u << 16); }
DEV unsigned short f2bf_bits(float x) { return __builtin_bit_cast(unsigned short, __float2bfloat16(x)); }

// ---------------------------------------------------------------------------
// NT bf16 MFMA GEMM, 128x128 tile, BK=32, 4 waves, software-pipelined staging.
// z decode: batch = z % zBatches; rem = z / zBatches; pi = rem&1 selects the
// (A0,B0)/(A1,B1) pair; kh = rem>>1 gives K-piece offset kh*kPiece.
// Epilogue goes through an LDS transpose so every global store is a full
// 256B-contiguous segment per 16-lane group (fixes HBM write amplification).
// epi: 0 = fp32 C = v            (v = acc*scale)
//      1 = bf16 C = v + bias[col]
//      2 = fp32 C = relu(v + bias[col] + add0..3[idx])   (adds non-null)
// ---------------------------------------------------------------------------
__global__ __launch_bounds__(256) void gemm_nt_kernel(
    const __hip_bfloat16* __restrict__ A0, const __hip_bfloat16* __restrict__ A1,
    int lda, long long sA,
    const __hip_bfloat16* __restrict__ B0, const __hip_bfloat16* __restrict__ B1,
    int ldb, long long sB,
    void* __restrict__ Cv, int ldc, long long sC, long long cOff, long long pieceCs,
    int K, int kPiece, int zBatches,
    float scale, const float* __restrict__ bias,
    const float* __restrict__ add0, const float* __restrict__ add1,
    const float* __restrict__ add2, const float* __restrict__ add3,
    int epi)
{
    __shared__ __align__(16) char smem[20480];     // K-loop: smA|smB; epilogue: transpose
    short* smA = (short*)smem;                     // 128 x 40 shorts = 10240 B
    short* smB = (short*)(smem + 10240);

    const int tid = threadIdx.x;
    const int wid = tid >> 6;
    const int lane = tid & 63;
    const int z = blockIdx.z;
    const int batch = z % zBatches;
    const int rem = z / zBatches;
    const int pi = rem & 1;
    const int kh = rem >> 1;

    const short* Ab = (const short*)(pi ? A1 : A0) + (size_t)batch * sA
                    + (size_t)blockIdx.x * 128 * lda + (size_t)kh * kPiece;
    const short* Bb = (const short*)(pi ? B1 : B0) + (size_t)batch * sB
                    + (size_t)blockIdx.y * 128 * ldb + (size_t)kh * kPiece;

    const int wm = (wid >> 1) * 64;
    const int wn = (wid & 1) * 64;
    const int fr = lane & 15;            // fragment row (m or n)
    const int kq = (lane >> 4) * 8;      // k-offset of this lane's 8 elems
    const int sr = tid >> 2;             // staging row 0..63 (plus h*64)
    const int sc = (tid & 3) * 8;        // staging short-col

    f32x4_t acc[4][4] = {};
    int4 avv[2], bvv[2];
#pragma unroll
    for (int h = 0; h < 2; h++) {        // prologue: tile 0
        const int row = h * 64 + sr;
        avv[h] = *(const int4*)(Ab + (size_t)row * lda + sc);
        bvv[h] = *(const int4*)(Bb + (size_t)row * ldb + sc);
    }

    for (int k0 = 0; k0 < K; k0 += 32) {
        __syncthreads();                 // prior tile's ds_reads complete
#pragma unroll
        for (int h = 0; h < 2; h++) {
            const int row = h * 64 + sr;
            *(int4*)&smA[row * LDA_S + sc] = avv[h];
            *(int4*)&smB[row * LDA_S + sc] = bvv[h];
        }
        __syncthreads();

        const int kn = k0 + 32;          // prefetch next tile (overlaps MFMA)
        if (kn < K) {
#pragma unroll
            for (int h = 0; h < 2; h++) {
                const int row = h * 64 + sr;
                avv[h] = *(const int4*)(Ab + (size_t)row * lda + (kn + sc));
                bvv[h] = *(const int4*)(Bb + (size_t)row * ldb + (kn + sc));
            }
        }

        bf16x8_t af[4], bfv[4];
#pragma unroll
        for (int i = 0; i < 4; i++)
            af[i] = *(const bf16x8_t*)&smA[(wm + i * 16 + fr) * LDA_S + kq];
#pragma unroll
        for (int j = 0; j < 4; j++)
            bfv[j] = *(const bf16x8_t*)&smB[(wn + j * 16 + fr) * LDA_S + kq];
#pragma unroll
        for (int i = 0; i < 4; i++)
#pragma unroll
            for (int j = 0; j < 4; j++)
                acc[i][j] = __builtin_amdgcn_mfma_f32_16x16x32_bf16(af[i], bfv[j], acc[i][j], 0, 0, 0);
    }

    // ---- epilogue: LDS transpose -> contiguous vectorized stores ----------
    float* lts = (float*)smem + wid * (16 * EPI_S);   // 4352 B per wave
    const int r_ = lane >> 4;            // 0..3
#pragma unroll
    for (int i = 0; i < 4; i++) {
        __syncthreads();
#pragma unroll
        for (int j = 0; j < 4; j++)
#pragma unroll
            for (int r = 0; r < 4; r++)
                lts[(r_ * 4 + r) * EPI_S + j * 16 + fr] = acc[i][j][r] * scale;
        __syncthreads();
#pragma unroll
        for (int t = 0; t < 4; t++) {
            const int lrow = t * 4 + r_;
            const f32x4_t v4 = *(const f32x4_t*)&lts[lrow * EPI_S + fr * 4];
            const int row = blockIdx.x * 128 + wm + i * 16 + lrow;
            const int col = blockIdx.y * 128 + wn + fr * 4;
            const size_t idx = (size_t)batch * sC + (size_t)row * ldc + col;
            const size_t gidx = (size_t)cOff + (size_t)rem * pieceCs + idx;
            if (epi == 0) {
                *(f32x4_t*)((float*)Cv + gidx) = v4;
            } else if (epi == 1) {
                f32x4_t bb = {0.f, 0.f, 0.f, 0.f};
                if (bias) bb = *(const f32x4_t*)(bias + col);
                ushort4 pk;
                pk.x = f2bf_bits(v4[0] + bb[0]);
                pk.y = f2bf_bits(v4[1] + bb[1]);
                pk.z = f2bf_bits(v4[2] + bb[2]);
                pk.w = f2bf_bits(v4[3] + bb[3]);
                *(ushort4*)((unsigned short*)Cv + gidx) = pk;
            } else {
                const f32x4_t bb = *(const f32x4_t*)(bias + col);
                const f32x4_t m0 = *(const f32x4_t*)(add0 + idx);
                const f32x4_t m1 = *(const f32x4_t*)(add1 + idx);
                const f32x4_t m2 = *(const f32x4_t*)(add2 + idx);
                const f32x4_t m3 = *(const f32x4_t*)(add3 + idx);
                f32x4_t o;
#pragma unroll
                for (int k = 0; k < 4; k++) {
                    float v = v4[k] + bb[k] + m0[k] + m1[k] + m2[k] + m3[k];
                    o[k] = v > 0.0f ? v : 0.0f;
                }
                *(f32x4_t*)((float*)Cv + gidx) = o;
            }
        }
    }
}

// ---------------------------------------------------------------------------
// Weight convert+transpose, all 5 weights in one dispatch (z selects).
// ---------------------------------------------------------------------------
__global__ __launch_bounds__(256) void wt_transpose_kernel(
    const float* __restrict__ W0, const float* __restrict__ W1,
    const float* __restrict__ W2, const float* __restrict__ W3,
    const float* __restrict__ W4, __hip_bfloat16* __restrict__ out)
{
    const int z = blockIdx.z;
    const float* in = z == 0 ? W0 : z == 1 ? W1 : z == 2 ? W2 : z == 3 ? W3 : W4;
    __hip_bfloat16* o = out + (size_t)z * D_ * D_;
    __shared__ float t[32][33];
    const int r0 = blockIdx.x * 32, c0 = blockIdx.y * 32;
    const int tx = threadIdx.x & 31, ty = threadIdx.x >> 5;
#pragma unroll
    for (int k = 0; k < 4; k++) {
        int r = ty + k * 8;
        t[r][tx] = in[(size_t)(r0 + r) * D_ + (c0 + tx)];
    }
    __syncthreads();
#pragma unroll
    for (int k = 0; k < 4; k++) {
        int r = ty + k * 8;
        o[(size_t)(c0 + r) * D_ + (r0 + tx)] = __float2bfloat16(t[tx][r]);
    }
}

// bf16 transpose for V: out[c][r] = in[r][c], batched over z.
__global__ __launch_bounds__(256) void transpose_bf16_kernel(
    const __hip_bfloat16* __restrict__ in, __hip_bfloat16* __restrict__ out,
    int R, int Cc, long long sIn, long long sOut)
{
    __shared__ short t[32][33];
    const size_t bz = blockIdx.z;
    const short* I = (const short*)in + bz * (size_t)sIn;
    short* O = (short*)out + bz * (size_t)sOut;
    const int r0 = blockIdx.x * 32, c0 = blockIdx.y * 32;
    const int tx = threadIdx.x & 31, ty = threadIdx.x >> 5;
#pragma unroll
    for (int k = 0; k < 4; k++) {
        int r = ty + k * 8;
        t[r][tx] = I[(size_t)(r0 + r) * Cc + (c0 + tx)];
    }
    __syncthreads();
#pragma unroll
    for (int k = 0; k < 4; k++) {
        int r = ty + k * 8;
        O[(size_t)(c0 + r) * R + (r0 + tx)] = t[tx][r];
    }
}

// all 3 modality inputs fp32 -> bf16, one dispatch
__global__ void cvt3_kernel(const float* __restrict__ x0, const float* __restrict__ x1,
                            const float* __restrict__ x2, __hip_bfloat16* __restrict__ dst)
{
    const int z = blockIdx.z;
    const float* s = z == 0 ? x0 : z == 1 ? x1 : x2;
    const long long i = (long long)blockIdx.x * 256 + threadIdx.x;
    dst[(size_t)z * BND_ + i] = __float2bfloat16(s[i]);
}

__global__ void zero_kernel(float* __restrict__ p, int n)
{
    const int i = blockIdx.x * 256 + threadIdx.x;
    if (i < n) p[i] = 0.0f;
}

// ---------------------------------------------------------------------------
// Hypergraph pipeline, batched over 3 modalities via blockIdx.z
// ---------------------------------------------------------------------------
__global__ void hg_count_kernel(const int* __restrict__ i0, const int* __restrict__ i1,
                                const int* __restrict__ i2,
                                int* __restrict__ Ddeg, int* __restrict__ Edeg)
{
    const int z = blockIdx.z;
    const int* idx = z == 0 ? i0 : z == 1 ? i1 : i2;
    const int c = blockIdx.x * 256 + threadIdx.x;
    atomicAdd(&Ddeg[z * N_ + idx[c]], 1);
    atomicAdd(&Edeg[z * M_ + idx[C_ + c]], 1);
}

__global__ __launch_bounds__(1024) void hg_scan_kernel(
    const int* __restrict__ deg, int* __restrict__ offs,
    float* __restrict__ inv, int* __restrict__ cnt, int len)
{
    const int z = blockIdx.z;
    deg += z * len; offs += z * (len + 1); inv += z * len; cnt += z * len;
    __shared__ int tmp[1024];
    const int t = threadIdx.x;
    const int v = deg[t];
    tmp[t] = v;
    __syncthreads();
    for (int o = 1; o < len; o <<= 1) {
        int x = (t >= o) ? tmp[t - o] : 0;
        __syncthreads();
        tmp[t] += x;
        __syncthreads();
    }
    offs[t] = tmp[t] - v;
    if (t == len - 1) offs[len] = tmp[t];
    inv[t] = (v > 0) ? (1.0f / (float)v) : 0.0f;
    cnt[t] = 0;
}

__global__ void hg_fill_kernel(const int* __restrict__ i0, const int* __restrict__ i1,
                               const int* __restrict__ i2,
                               const int* __restrict__ noffs, const int* __restrict__ eoffs,
                               int* __restrict__ ncnt, int* __restrict__ ecnt,
                               int* __restrict__ nord, int* __restrict__ eord)
{
    const int z = blockIdx.z;
    const int* nidx = z == 0 ? i0 : z == 1 ? i1 : i2;
    const int* eidx = nidx + C_;
    noffs += z * (N_ + 1); eoffs += z * (M_ + 1);
    ncnt += z * N_; ecnt += z * M_; nord += z * C_; eord += z * C_;
    const int c = blockIdx.x * 256 + threadIdx.x;
    const int nd = nidx[c], ed = eidx[c];
    const int p1 = atomicAdd(&ncnt[nd], 1);
    nord[noffs[nd] + p1] = c;
    const int p2 = atomicAdd(&ecnt[ed], 1);
    eord[eoffs[ed] + p2] = c;
}

// s1/s2 from bf16 xp; one wave per (md,b,n)
__global__ __launch_bounds__(64) void hg_s12_kernel(
    const unsigned short* __restrict__ Xp, const float* __restrict__ att,
    float* __restrict__ s1, float* __restrict__ s2)
{
    const int z = blockIdx.z;
    const int bid = blockIdx.x;
    const int b = bid >> 10;
    const int n = bid & (N_ - 1);
    const int lane = threadIdx.x;
    const unsigned short* xr = Xp + (size_t)z * BND_ + (size_t)(b * N_ + n) * D_;
    const ushort4 u = ((const ushort4*)xr)[lane];
    const float4 a1 = ((const float4*)att)[lane];
    const float4 a2 = ((const float4*)(att + D_))[lane];
    float d1 = bf2f(u.x) * a1.x + bf2f(u.y) * a1.y + bf2f(u.z) * a1.z + bf2f(u.w) * a1.w;
    float d2 = bf2f(u.x) * a2.x + bf2f(u.y) * a2.y + bf2f(u.z) * a2.z + bf2f(u.w) * a2.w;
#pragma unroll
    for (int o = 32; o > 0; o >>= 1) { d1 += __shfl_down(d1, o); d2 += __shfl_down(d2, o); }
    if (lane == 0) { s1[z * NB_ + n * 16 + b] = d1; s2[z * NB_ + n * 16 + b] = d2; }
}

// edge_s2[m,b]: atomic-free, grid (M_,1,3), 16 pos x 16 b LDS reduce.
__global__ __launch_bounds__(256) void hg_edge_s2_kernel(
    const int* __restrict__ i0, const int* __restrict__ i1, const int* __restrict__ i2,
    const int* __restrict__ eoffs, const int* __restrict__ eord,
    const float* __restrict__ s2, float* __restrict__ edge_s2)
{
    const int z = blockIdx.z;
    const int* nidx = z == 0 ? i0 : z == 1 ? i1 : i2;
    eoffs += z * (M_ + 1); eord += z * C_;
    s2 += z * NB_; edge_s2 += (size_t)z * M_ * 16;

    const int m = blockIdx.x;
    const int pos = threadIdx.x >> 4;
    const int b = threadIdx.x & 15;
    const int base = eoffs[m];
    const int len = eoffs[m + 1] - base;
    float acc = 0.0f;
#pragma unroll 4
    for (int i = pos; i < len; i += 16) {
        int c = eord[base + i];
        acc += s2[nidx[c] * 16 + b];
    }
    __shared__ float red[16][16];
    red[pos][b] = acc;
    __syncthreads();
    for (int s = 8; s > 0; s >>= 1) {
        if (pos < s) red[pos][b] += red[pos + s][b];
        __syncthreads();
    }
    if (pos == 0) edge_s2[m * 16 + b] = red[0][b];
}

__global__ __launch_bounds__(256) void hg_node_softmax_kernel(
    const int* __restrict__ i0, const int* __restrict__ i1, const int* __restrict__ i2,
    const int* __restrict__ noffs, const int* __restrict__ nord,
    const float* __restrict__ s1, const float* __restrict__ edge_s2,
    float* __restrict__ ee, float* __restrict__ inv_sum)
{
    const int z = blockIdx.z;
    const int* eidx = (z == 0 ? i0 : z == 1 ? i1 : i2) + C_;
    noffs += z * (N_ + 1); nord += z * C_;
    s1 += z * NB_; edge_s2 += (size_t)z * M_ * 16;
    ee += (size_t)z * C_ * 16; inv_sum += z * NB_;

    const int n = blockIdx.x;
    const int base = noffs[n];
    const int len = noffs[n + 1] - base;
    if (len == 0) return;
    const int cp = threadIdx.x >> 4;
    const int b = threadIdx.x & 15;
    __shared__ float red[16][16];
    const float s1nb = s1[n * 16 + b];

    float mx = -1e30f;
    for (int i = cp; i < len; i += 16) {
        int c = nord[base + i];
        float e = s1nb + edge_s2[eidx[c] * 16 + b];
        e = e > 0.0f ? e : 0.2f * e;      // leaky_relu 0.2
        mx = fmaxf(mx, e);
    }
    red[cp][b] = mx;
    __syncthreads();
    for (int s = 8; s > 0; s >>= 1) {
        if (cp < s) red[cp][b] = fmaxf(red[cp][b], red[cp + s][b]);
        __syncthreads();
    }
    mx = red[0][b];
    __syncthreads();

    float sm = 0.0f;
    for (int i = cp; i < len; i += 16) {
        int c = nord[base + i];
        float e = s1nb + edge_s2[eidx[c] * 16 + b];
        e = e > 0.0f ? e : 0.2f * e;
        float ex = __expf(e - mx);
        ee[c * 16 + b] = ex;
        sm += ex;
    }
    red[cp][b] = sm;
    __syncthreads();
    for (int s = 8; s > 0; s >>= 1) {
        if (cp < s) red[cp][b] += red[cp + s][b];
        __syncthreads();
    }
    if (cp == 0) inv_sum[n * 16 + b] = 1.0f / (red[0][b] + 1e-16f);
}

// Pack sorted-order gather arrays (kills dependent chains in xedge/xnode).
__global__ __launch_bounds__(256) void hg_pack_kernel(
    const int* __restrict__ i0, const int* __restrict__ i1, const int* __restrict__ i2,
    const int* __restrict__ nord, const int* __restrict__ eord,
    const float* __restrict__ ee, const float* __restrict__ inv_sum,
    int* __restrict__ EmS, int* __restrict__ NnS,
    float* __restrict__ CoefN, float* __restrict__ CoefE)
{
    const int z = blockIdx.z;
    const int* nidx = z == 0 ? i0 : z == 1 ? i1 : i2;
    const int* eidx = nidx + C_;
    nord += z * C_; eord += z * C_;
    ee += (size_t)z * C_ * 16; inv_sum += z * NB_;
    EmS += z * C_; NnS += z * C_;
    CoefN += (size_t)z * C_ * 16; CoefE += (size_t)z * C_ * 16;

    const int gid = blockIdx.x * 256 + threadIdx.x;   // C*16
    const int i = gid >> 4, b = gid & 15;
    const int c1 = nord[i], c2 = eord[i];
    const int n1 = nidx[c1], n2 = nidx[c2];
    if (b == 0) { EmS[i] = eidx[c1]; NnS[i] = n2; }
    CoefN[i * 16 + b] = ee[c1 * 16 + b] * inv_sum[n1 * 16 + b];
    CoefE[i * 16 + b] = ee[c2 * 16 + b] * inv_sum[n2 * 16 + b];
}

// x_edge[m,b,:] via packed arrays.
__global__ __launch_bounds__(256) void hg_xedge_kernel(
    const int* __restrict__ eoffs, const int* __restrict__ NnS,
    const float* __restrict__ CoefE, const unsigned short* __restrict__ Xp,
    const float* __restrict__ Bnorm, float* __restrict__ x_edge)
{
    const int z = blockIdx.z;
    eoffs += z * (M_ + 1); NnS += z * C_;
    CoefE += (size_t)z * C_ * 16;
    const unsigned short* xp = Xp + (size_t)z * BND_;
    Bnorm += z * M_; x_edge += (size_t)z * M_ * B_ * D_;

    const int m = blockIdx.x >> 4;
    const int b = blockIdx.x & 15;
    const int d = threadIdx.x;
    const int base = eoffs[m];
    const int len = eoffs[m + 1] - base;
    float acc = 0.0f;
#pragma unroll 4
    for (int i = 0; i < len; i++) {
        const int nn = NnS[base + i];
        const float cf = CoefE[(size_t)(base + i) * 16 + b];
        acc += cf * bf2f(xp[(size_t)(b * N_ + nn) * D_ + d]);
    }
    x_edge[((size_t)(m * 16 + b)) * D_ + d] = Bnorm[m] * acc;
}

// h[b,n,:] via packed arrays.
__global__ __launch_bounds__(256) void hg_xnode_kernel(
    const int* __restrict__ noffs, const int* __restrict__ EmS,
    const float* __restrict__ CoefN, const float* __restrict__ x_edge,
    const float* __restrict__ Dinv, __hip_bfloat16* __restrict__ Hbf)
{
    const int z = blockIdx.z;
    noffs += z * (N_ + 1); EmS += z * C_;
    CoefN += (size_t)z * C_ * 16;
    x_edge += (size_t)z * M_ * B_ * D_; Dinv += z * N_;
    __hip_bfloat16* hbf = Hbf + (size_t)z * BND_;

    const int n = blockIdx.x >> 4;
    const int b = blockIdx.x & 15;
    const int d = threadIdx.x;
    const int base = noffs[n];
    const int len = noffs[n + 1] - base;
    float acc = 0.0f;
#pragma unroll 4
    for (int i = 0; i < len; i++) {
        const int em = EmS[base + i];
        const float cf = CoefN[(size_t)(base + i) * 16 + b];
        acc += cf * x_edge[((size_t)(em * 16 + b)) * D_ + d];
    }
    hbf[((size_t)(b * N_ + n)) * D_ + d] = __float2bfloat16(Dinv[n] * acc);
}

// ---------------------------------------------------------------------------
// Row softmax over bf16 S (1024 cols), in place. One wave per row, shfl_xor
// reductions only — no LDS, no barriers. grid = rows/4, block 256.
// ---------------------------------------------------------------------------
__global__ __launch_bounds__(256) void attn_softmax_kernel(unsigned short* __restrict__ S)
{
    const int wid = threadIdx.x >> 6, lane = threadIdx.x & 63;
    const size_t row = (size_t)blockIdx.x * 4 + wid;
    unsigned short* p = S + row * 1024 + lane * 16;
    u16x8_t a = *(const u16x8_t*)p;
    u16x8_t b = *(const u16x8_t*)(p + 8);
    float v[16];
#pragma unroll
    for (int k = 0; k < 8; k++) { v[k] = bf2f(a[k]); v[8 + k] = bf2f(b[k]); }
    float mx = v[0];
#pragma unroll
    for (int k = 1; k < 16; k++) mx = fmaxf(mx, v[k]);
#pragma unroll
    for (int o = 32; o > 0; o >>= 1) mx = fmaxf(mx, __shfl_xor(mx, o));
    float s = 0.0f;
#pragma unroll
    for (int k = 0; k < 16; k++) { v[k] = __expf(v[k] - mx); s += v[k]; }
#pragma unroll
    for (int o = 32; o > 0; o >>= 1) s += __shfl_xor(s, o);
    const float inv = 1.0f / s;
#pragma unroll
    for (int k = 0; k < 8; k++) { a[k] = f2bf_bits(v[k] * inv); b[k] = f2bf_bits(v[8 + k] * inv); }
    *(u16x8_t*)p = a;
    *(u16x8_t*)(p + 8) = b;
}

// ---------------------------------------------------------------------------
// Host
// ---------------------------------------------------------------------------
static inline void launch_gemm(hipStream_t s, dim3 grid,
                               const void* A0, const void* A1, int lda, long long sA,
                               const void* B0, const void* B1, int ldb, long long sB,
                               void* Cv, int ldc, long long sC, long long cOff, long long pieceCs,
                               int K, int kPiece, int zBatches,
                               float scale, const float* bias,
                               const float* a0, const float* a1,
                               const float* a2, const float* a3, int epi)
{
    gemm_nt_kernel<<<grid, 256, 0, s>>>((const __hip_bfloat16*)A0, (const __hip_bfloat16*)A1,
                                        lda, sA,
                                        (const __hip_bfloat16*)B0, (const __hip_bfloat16*)B1,
                                        ldb, sB,
                                        Cv, ldc, sC, cOff, pieceCs, K, kPiece, zBatches,
                                        scale, bias, a0, a1, a2, a3, epi);
}

extern "C" void kernel_launch(void* const* d_in, const int* in_sizes, int n_in,
                              void* d_out, int out_size, void* d_ws, size_t ws_size,
                              hipStream_t stream)
{
    (void)in_sizes; (void)n_in; (void)out_size; (void)ws_size;

    const float* x0 = (const float*)d_in[0];
    const float* x1 = (const float*)d_in[1];
    const float* x2 = (const float*)d_in[2];
    const int* h0 = (const int*)d_in[3];
    const int* h1 = (const int*)d_in[4];
    const int* h2 = (const int*)d_in[5];
    const float* W_hg  = (const float*)d_in[6];
    const float* att_hg= (const float*)d_in[7];
    const float* WQ = (const float*)d_in[8];
    const float* bQ = (const float*)d_in[9];
    const float* WK = (const float*)d_in[10];
    const float* bK = (const float*)d_in[11];
    const float* WV = (const float*)d_in[12];
    const float* bV = (const float*)d_in[13];
    const float* WO = (const float*)d_in[14];
    const float* bO = (const float*)d_in[15];
    float* outp = (float*)d_out;

    char* ws = (char*)d_ws;
    size_t off = 0;
    auto take = [&](size_t bytes) { size_t r = off; off += (bytes + 255) & ~(size_t)255; return r; };

    const size_t oWt   = take((size_t)5 * D_ * D_ * 2);          // 0.63 MB
    const size_t oHbf  = take((size_t)3 * BND_ * 2);             // 24 MB
    const size_t oKall = take((size_t)3 * BND_ * 2);             // 24 MB
    const size_t oVt   = take((size_t)3 * BND_ * 2);             // 24 MB
    const size_t oQb   = take((size_t)BND_ * 2);                 // 8 MB
    const size_t oS    = take((size_t)64 * 1024 * 1024);         // S(2 partners) | Xc+Xp | Vtmp
    const size_t oMsg  = take((size_t)4 * BND_ * 4);             // 64 MB (4 PV pieces)
    const size_t oXe   = take((size_t)3 * M_ * B_ * D_ * 4);     // 6 MB
    const size_t oEE   = take((size_t)3 * C_ * 16 * 4);          // 1.5 MB
    const size_t oCoefN= take((size_t)3 * C_ * 16 * 4);          // 1.5 MB
    const size_t oCoefE= take((size_t)3 * C_ * 16 * 4);          // 1.5 MB
    const size_t oEmS  = take((size_t)3 * C_ * 4);
    const size_t oNnS  = take((size_t)3 * C_ * 4);
    const size_t oS1   = take((size_t)3 * NB_ * 4);
    const size_t oS2   = take((size_t)3 * NB_ * 4);
    const size_t oInv  = take((size_t)3 * NB_ * 4);
    const size_t oZero = take((size_t)3 * (N_ + M_) * 4);        // Ddeg|Edeg only
    const size_t oEs2  = take((size_t)3 * M_ * 16 * 4);
    const size_t oNOffs= take((size_t)3 * (N_ + 1) * 4);
    const size_t oEOffs= take((size_t)3 * (M_ + 1) * 4);
    const size_t oNCnt = take((size_t)3 * N_ * 4);
    const size_t oECnt = take((size_t)3 * M_ * 4);
    const size_t oNOrd = take((size_t)3 * C_ * 4);
    const size_t oEOrd = take((size_t)3 * C_ * 4);
    const size_t oDinv = take((size_t)3 * N_ * 4);
    const size_t oBnorm= take((size_t)3 * M_ * 4);

    __hip_bfloat16* Wt   = (__hip_bfloat16*)(ws + oWt);
    __hip_bfloat16* Hbf  = (__hip_bfloat16*)(ws + oHbf);
    __hip_bfloat16* Kall = (__hip_bfloat16*)(ws + oKall);
    __hip_bfloat16* Vt   = (__hip_bfloat16*)(ws + oVt);
    __hip_bfloat16* Qb   = (__hip_bfloat16*)(ws + oQb);
    __hip_bfloat16* Xc   = (__hip_bfloat16*)(ws + oS);
    __hip_bfloat16* Xp   = (__hip_bfloat16*)(ws + oS + (size_t)3 * BND_ * 2);
    __hip_bfloat16* Vtmp = (__hip_bfloat16*)(ws + oS);
    __hip_bfloat16* Sb   = (__hip_bfloat16*)(ws + oS);
    float* Msg  = (float*)(ws + oMsg);
    float* Xe   = (float*)(ws + oXe);
    float* EE   = (float*)(ws + oEE);
    float* CoefN= (float*)(ws + oCoefN);
    float* CoefE= (float*)(ws + oCoefE);
    int*   EmS  = (int*)(ws + oEmS);
    int*   NnS  = (int*)(ws + oNnS);
    float* S1f  = (float*)(ws + oS1);
    float* S2f  = (float*)(ws + oS2);
    float* Inv  = (float*)(ws + oInv);
    int*   Ddeg = (int*)(ws + oZero);
    int*   Edeg = (int*)(ws + oZero + (size_t)3 * N_ * 4);
    float* Es2  = (float*)(ws + oEs2);
    const int zeroWords = 3 * (N_ + M_);
    int*   NOffs = (int*)(ws + oNOffs);
    int*   EOffs = (int*)(ws + oEOffs);
    int*   NCnt  = (int*)(ws + oNCnt);
    int*   ECnt  = (int*)(ws + oECnt);
    int*   NOrd  = (int*)(ws + oNOrd);
    int*   EOrd  = (int*)(ws + oEOrd);
    float* Dinv  = (float*)(ws + oDinv);
    float* Bnorm = (float*)(ws + oBnorm);

    const int WN = D_ * D_;
    __hip_bfloat16* WtHG = Wt;
    __hip_bfloat16* WtQ  = Wt + (size_t)WN;
    __hip_bfloat16* WtK  = Wt + (size_t)2 * WN;
    __hip_bfloat16* WtV  = Wt + (size_t)3 * WN;
    __hip_bfloat16* WtO  = Wt + (size_t)4 * WN;

    // -------- Phase 0: weights (one dispatch) -------------------------------
    wt_transpose_kernel<<<dim3(8, 8, 5), 256, 0, stream>>>(W_hg, WQ, WK, WV, WO, Wt);

    // -------- Phase 1: hypergraph conv, all modalities batched --------------
    cvt3_kernel<<<dim3((unsigned)(BND_ / 256), 1, 3), 256, 0, stream>>>(x0, x1, x2, Xc);
    zero_kernel<<<(zeroWords + 255) / 256, 256, 0, stream>>>((float*)(ws + oZero), zeroWords);
    hg_count_kernel<<<dim3(C_ / 256, 1, 3), 256, 0, stream>>>(h0, h1, h2, Ddeg, Edeg);
    hg_scan_kernel<<<dim3(1, 1, 3), N_, 0, stream>>>(Ddeg, NOffs, Dinv, NCnt, N_);
    hg_scan_kernel<<<dim3(1, 1, 3), M_, 0, stream>>>(Edeg, EOffs, Bnorm, ECnt, M_);
    hg_fill_kernel<<<dim3(C_ / 256, 1, 3), 256, 0, stream>>>(h0, h1, h2, NOffs, EOffs,
                                                             NCnt, ECnt, NOrd, EOrd);
    launch_gemm(stream, dim3(BN_ / 128, D_ / 128, 3),
                Xc, Xc, D_, BND_, WtHG, WtHG, D_, 0,
                Xp, D_, BND_, 0, 0, D_, D_, 3,
                1.0f, nullptr, nullptr, nullptr, nullptr, nullptr, 1);
    hg_s12_kernel<<<dim3(BN_, 1, 3), 64, 0, stream>>>((const unsigned short*)Xp, att_hg, S1f, S2f);
    hg_edge_s2_kernel<<<dim3(M_, 1, 3), 256, 0, stream>>>(h0, h1, h2, EOffs, EOrd, S2f, Es2);
    hg_node_softmax_kernel<<<dim3(N_, 1, 3), 256, 0, stream>>>(h0, h1, h2, NOffs, NOrd,
                                                               S1f, Es2, EE, Inv);
    hg_pack_kernel<<<dim3(C_ * 16 / 256, 1, 3), 256, 0, stream>>>(h0, h1, h2, NOrd, EOrd,
                                                                  EE, Inv, EmS, NnS, CoefN, CoefE);
    hg_xedge_kernel<<<dim3(M_ * B_, 1, 3), 256, 0, stream>>>(EOffs, NnS, CoefE,
                                                             (const unsigned short*)Xp, Bnorm, Xe);
    hg_xnode_kernel<<<dim3(N_ * B_, 1, 3), 256, 0, stream>>>(NOffs, EmS, CoefN, Xe, Dinv, Hbf);

    // -------- Phase 2: K, V for all 3 modalities ----------------------------
    launch_gemm(stream, dim3(3 * BN_ / 128, D_ / 128, 1),
                Hbf, Hbf, D_, 0, WtK, WtK, D_, 0,
                Kall, D_, 0, 0, 0, D_, D_, 1,
                1.0f, bK, nullptr, nullptr, nullptr, nullptr, 1);
    launch_gemm(stream, dim3(3 * BN_ / 128, D_ / 128, 1),
                Hbf, Hbf, D_, 0, WtV, WtV, D_, 0,
                Vtmp, D_, 0, 0, 0, D_, D_, 1,
                1.0f, bV, nullptr, nullptr, nullptr, nullptr, 1);
    transpose_bf16_kernel<<<dim3(N_ / 32, D_ / 32, 48), 256, 0, stream>>>(
        Vtmp, Vt, N_, D_, (long long)N_ * D_, (long long)D_ * N_);

    // -------- Phase 3: cross-modal attention + output -----------------------
    const long long NN = (long long)N_ * N_;
    for (int m = 0; m < 3; m++) {
        const __hip_bfloat16* hm = Hbf + (size_t)m * BND_;
        const int pn0 = (m == 0) ? 1 : 0;
        const int pn1 = (m == 2) ? 1 : 2;
        launch_gemm(stream, dim3(BN_ / 128, D_ / 128, 1),
                    hm, hm, D_, 0, WtQ, WtQ, D_, 0,
                    Qb, D_, 0, 0, 0, D_, D_, 1,
                    1.0f, bQ, nullptr, nullptr, nullptr, nullptr, 1);
        launch_gemm(stream, dim3(N_ / 128, N_ / 128, 32),
                    Qb, Qb, D_, (long long)N_ * D_,
                    Kall + (size_t)pn0 * BND_, Kall + (size_t)pn1 * BND_, D_, (long long)N_ * D_,
                    Sb, N_, NN, 0, 16LL * NN, D_, D_, 16,
                    0.0625f, nullptr, nullptr, nullptr, nullptr, nullptr, 1);
        attn_softmax_kernel<<<2 * B_ * N_ / 4, 256, 0, stream>>>((unsigned short*)Sb);
        launch_gemm(stream, dim3(N_ / 128, D_ / 128, 64),
                    Sb, Sb + (size_t)16 * NN, N_, NN,
                    Vt + (size_t)pn0 * BND_, Vt + (size_t)pn1 * BND_, N_, (long long)D_ * N_,
                    Msg, D_, (long long)N_ * D_, 0, BND_, 512, 512, 16,
                    1.0f, nullptr, nullptr, nullptr, nullptr, nullptr, 0);
        launch_gemm(stream, dim3(BN_ / 128, D_ / 128, 1),
                    hm, hm, D_, 0, WtO, WtO, D_, 0,
                    outp, D_, 0, (long long)m * BND_, 0, D_, D_, 1,
                    1.0f, bO, Msg, Msg + BND_, Msg + 2 * BND_, Msg + 3 * BND_, 2);
    }
}

// Round 9
// 866.416 us; speedup vs baseline: 2.0048x; 1.3491x over previous
//
#include <hip/hip_runtime.h>
#include <hip/hip_bf16.h>
#include <stdint.h>

// ---------------------------------------------------------------------------
// B=16, N=1024, D=256, M=128, C=8192. fp32 in/out, bf16 MFMA internally.
// Output: 3 x [B,N,D] fp32 concatenated.
// Attention is fully fused (flash-style): S never touches HBM.
// ---------------------------------------------------------------------------

namespace {
constexpr int B_ = 16;
constexpr int N_ = 1024;
constexpr int D_ = 256;
constexpr int M_ = 128;
constexpr int C_ = 8192;
constexpr int BN_ = B_ * N_;                       // 16384
constexpr long long BND_ = (long long)BN_ * D_;    // 4,194,304 elems
constexpr int NB_ = N_ * B_;                       // 16384
constexpr int LDA_S = 40;                          // K-loop LDS stride (shorts)
constexpr int EPI_S = 68;                          // epilogue LDS stride (floats)
}

typedef short bf16x8_t __attribute__((ext_vector_type(8)));
typedef float f32x4_t __attribute__((ext_vector_type(4)));
typedef unsigned short u16x8_t __attribute__((ext_vector_type(8)));

#define DEV static __device__ __forceinline__
DEV float bf2f(unsigned short u) { return __uint_as_float((unsigned)u << 16); }
DEV unsigned short f2bf_bits(float x) { return __builtin_bit_cast(unsigned short, __float2bfloat16(x)); }

// ---------------------------------------------------------------------------
// NT bf16 MFMA GEMM, 128x128 tile, BK=32, 4 waves, LDS-transposed epilogue.
// epi: 0 = fp32 C = v (v = acc*scale)
//      1 = bf16 C = v + bias[col]
//      2 = fp32 C = relu(v + bias[col] + add0[idx] + add1[idx])
//      4 = bf16 C = v + bias[col]*scale      (i.e. (acc+bias)*scale)
// ---------------------------------------------------------------------------
__global__ __launch_bounds__(256) void gemm_nt_kernel(
    const __hip_bfloat16* __restrict__ A0, const __hip_bfloat16* __restrict__ A1,
    int lda, long long sA,
    const __hip_bfloat16* __restrict__ B0, const __hip_bfloat16* __restrict__ B1,
    int ldb, long long sB,
    void* __restrict__ Cv, int ldc, long long sC, long long cOff, long long pieceCs,
    int K, int kPiece, int zBatches,
    float scale, const float* __restrict__ bias,
    const float* __restrict__ add0, const float* __restrict__ add1,
    int epi)
{
    __shared__ __align__(16) char smem[20480];
    short* smA = (short*)smem;
    short* smB = (short*)(smem + 10240);

    const int tid = threadIdx.x;
    const int wid = tid >> 6;
    const int lane = tid & 63;
    const int z = blockIdx.z;
    const int batch = z % zBatches;
    const int rem = z / zBatches;
    const int pi = rem & 1;
    const int kh = rem >> 1;

    const short* Ab = (const short*)(pi ? A1 : A0) + (size_t)batch * sA
                    + (size_t)blockIdx.x * 128 * lda + (size_t)kh * kPiece;
    const short* Bb = (const short*)(pi ? B1 : B0) + (size_t)batch * sB
                    + (size_t)blockIdx.y * 128 * ldb + (size_t)kh * kPiece;

    const int wm = (wid >> 1) * 64;
    const int wn = (wid & 1) * 64;
    const int fr = lane & 15;
    const int kq = (lane >> 4) * 8;
    const int sr = tid >> 2;
    const int sc = (tid & 3) * 8;

    f32x4_t acc[4][4] = {};
    int4 avv[2], bvv[2];
#pragma unroll
    for (int h = 0; h < 2; h++) {
        const int row = h * 64 + sr;
        avv[h] = *(const int4*)(Ab + (size_t)row * lda + sc);
        bvv[h] = *(const int4*)(Bb + (size_t)row * ldb + sc);
    }

    for (int k0 = 0; k0 < K; k0 += 32) {
        __syncthreads();
#pragma unroll
        for (int h = 0; h < 2; h++) {
            const int row = h * 64 + sr;
            *(int4*)&smA[row * LDA_S + sc] = avv[h];
            *(int4*)&smB[row * LDA_S + sc] = bvv[h];
        }
        __syncthreads();

        const int kn = k0 + 32;
        if (kn < K) {
#pragma unroll
            for (int h = 0; h < 2; h++) {
                const int row = h * 64 + sr;
                avv[h] = *(const int4*)(Ab + (size_t)row * lda + (kn + sc));
                bvv[h] = *(const int4*)(Bb + (size_t)row * ldb + (kn + sc));
            }
        }

        bf16x8_t af[4], bfv[4];
#pragma unroll
        for (int i = 0; i < 4; i++)
            af[i] = *(const bf16x8_t*)&smA[(wm + i * 16 + fr) * LDA_S + kq];
#pragma unroll
        for (int j = 0; j < 4; j++)
            bfv[j] = *(const bf16x8_t*)&smB[(wn + j * 16 + fr) * LDA_S + kq];
#pragma unroll
        for (int i = 0; i < 4; i++)
#pragma unroll
            for (int j = 0; j < 4; j++)
                acc[i][j] = __builtin_amdgcn_mfma_f32_16x16x32_bf16(af[i], bfv[j], acc[i][j], 0, 0, 0);
    }

    float* lts = (float*)smem + wid * (16 * EPI_S);
    const int r_ = lane >> 4;
#pragma unroll
    for (int i = 0; i < 4; i++) {
        __syncthreads();
#pragma unroll
        for (int j = 0; j < 4; j++)
#pragma unroll
            for (int r = 0; r < 4; r++)
                lts[(r_ * 4 + r) * EPI_S + j * 16 + fr] = acc[i][j][r] * scale;
        __syncthreads();
#pragma unroll
        for (int t = 0; t < 4; t++) {
            const int lrow = t * 4 + r_;
            const f32x4_t v4 = *(const f32x4_t*)&lts[lrow * EPI_S + fr * 4];
            const int row = blockIdx.x * 128 + wm + i * 16 + lrow;
            const int col = blockIdx.y * 128 + wn + fr * 4;
            const size_t idx = (size_t)batch * sC + (size_t)row * ldc + col;
            const size_t gidx = (size_t)cOff + (size_t)rem * pieceCs + idx;
            if (epi == 0) {
                *(f32x4_t*)((float*)Cv + gidx) = v4;
            } else if (epi == 1 || epi == 4) {
                f32x4_t bb = {0.f, 0.f, 0.f, 0.f};
                if (bias) bb = *(const f32x4_t*)(bias + col);
                const float bs = (epi == 4) ? scale : 1.0f;
                ushort4 pk;
                pk.x = f2bf_bits(v4[0] + bb[0] * bs);
                pk.y = f2bf_bits(v4[1] + bb[1] * bs);
                pk.z = f2bf_bits(v4[2] + bb[2] * bs);
                pk.w = f2bf_bits(v4[3] + bb[3] * bs);
                *(ushort4*)((unsigned short*)Cv + gidx) = pk;
            } else {
                const f32x4_t bb = *(const f32x4_t*)(bias + col);
                const f32x4_t m0 = *(const f32x4_t*)(add0 + idx);
                const f32x4_t m1 = *(const f32x4_t*)(add1 + idx);
                f32x4_t o;
#pragma unroll
                for (int k = 0; k < 4; k++) {
                    float v = v4[k] + bb[k] + m0[k] + m1[k];
                    o[k] = v > 0.0f ? v : 0.0f;
                }
                *(f32x4_t*)((float*)Cv + gidx) = o;
            }
        }
    }
}

// ---------------------------------------------------------------------------
// Fused flash attention: per block = 64 Q-rows of one (m,batch); both partners.
// Msg[p][m][b][n][d] fp32 = softmax(Q_m K_p^T /16) @ V_p   (unfused sum in out-GEMM)
// 4 waves; wave w owns Q rows [qt*64 + w*16, +16).
// ---------------------------------------------------------------------------
__global__ __launch_bounds__(256) void flash_attn_kernel(
    const __hip_bfloat16* __restrict__ Qall,   // [3][16][1024][256] bf16, pre-scaled by 1/16
    const __hip_bfloat16* __restrict__ Kall,   // [3][16][1024][256] bf16
    const __hip_bfloat16* __restrict__ Vt,     // [3][16][256][1024] bf16
    float* __restrict__ Msg)                   // [2][3][16][1024][256] fp32
{
    __shared__ __align__(16) short smK[128 * 40];        // 10240 B
    __shared__ __align__(16) short smV[256 * 40];        // 20480 B
    __shared__ __align__(16) char  smP[4 * 4352];        // per-wave P (bf16 16x136) / epi (f32 16x68)

    const int tid = threadIdx.x;
    const int w = tid >> 6;
    const int lane = tid & 63;
    const int fr = lane & 15;
    const int qd = lane >> 4;
    const int qt = blockIdx.x, batch = blockIdx.y, m = blockIdx.z;
    const int pn0 = (m == 0) ? 1 : 0;
    const int pn1 = (m == 2) ? 1 : 2;

    short* Pw = (short*)(smP + w * 4352);
    float* Ew = (float*)(smP + w * 4352);

    // Q fragments: A[m=fr][k=qd*8+j] for 8 d-chunks, wave rows qt*64+w*16+fr
    const size_t qrow = ((size_t)(m * 16 + batch) * 1024) + qt * 64 + w * 16 + fr;
    const short* qp = (const short*)Qall + qrow * 256 + qd * 8;
    bf16x8_t qa[8];
#pragma unroll
    for (int c = 0; c < 8; c++) qa[c] = *(const bf16x8_t*)(qp + c * 32);

    const int sr2 = tid >> 2;
    const int sc2 = (tid & 3) * 8;

    for (int p = 0; p < 2; p++) {
        const int pn = p == 0 ? pn0 : pn1;
        const short* Kb = (const short*)Kall + ((size_t)(pn * 16 + batch) * 1024) * 256;
        const short* Vb = (const short*)Vt + ((size_t)(pn * 16 + batch) * 256) * 1024;
        f32x4_t Op[16] = {};
        float mrun[4] = {-1e30f, -1e30f, -1e30f, -1e30f};
        float lrun[4] = {0.f, 0.f, 0.f, 0.f};

        for (int kt = 0; kt < 8; kt++) {
            // ---- S = Q K^T (over d, 8 chunks of 32) ----
            f32x4_t S[8] = {};
            for (int dc = 0; dc < 8; dc++) {
                __syncthreads();
#pragma unroll
                for (int it = 0; it < 2; it++) {
                    const int row = it * 64 + sr2;
                    *(int4*)&smK[row * 40 + sc2] =
                        *(const int4*)(Kb + (size_t)(kt * 128 + row) * 256 + dc * 32 + sc2);
                }
                __syncthreads();
#pragma unroll
                for (int f = 0; f < 8; f++) {
                    bf16x8_t kb = *(const bf16x8_t*)&smK[(f * 16 + fr) * 40 + qd * 8];
                    S[f] = __builtin_amdgcn_mfma_f32_16x16x32_bf16(qa[dc], kb, S[f], 0, 0, 0);
                }
            }
            // ---- online softmax (rows = qd*4+r, cols = f*16+fr) ----
            float alpha[4], tsum[4];
#pragma unroll
            for (int r = 0; r < 4; r++) {
                float mx = S[0][r];
#pragma unroll
                for (int f = 1; f < 8; f++) mx = fmaxf(mx, S[f][r]);
#pragma unroll
                for (int o = 1; o < 16; o <<= 1) mx = fmaxf(mx, __shfl_xor(mx, o));
                const float mnew = fmaxf(mrun[r], mx);
                alpha[r] = __expf(mrun[r] - mnew);
                mrun[r] = mnew;
                tsum[r] = 0.0f;
            }
#pragma unroll
            for (int f = 0; f < 8; f++) {
#pragma unroll
                for (int r = 0; r < 4; r++) {
                    const float pv = __expf(S[f][r] - mrun[r]);
                    tsum[r] += pv;
                    Pw[(qd * 4 + r) * 136 + f * 16 + fr] = (short)f2bf_bits(pv);
                }
            }
#pragma unroll
            for (int r = 0; r < 4; r++) {
                float s = tsum[r];
#pragma unroll
                for (int o = 1; o < 16; o <<= 1) s += __shfl_xor(s, o);
                lrun[r] = lrun[r] * alpha[r] + s;
            }
#pragma unroll
            for (int df = 0; df < 16; df++)
#pragma unroll
                for (int r = 0; r < 4; r++) Op[df][r] *= alpha[r];
            // ---- O += P @ V (4 kv-chunks of 32) ----
            for (int kc = 0; kc < 4; kc++) {
                __syncthreads();   // also orders the Pw writes above
#pragma unroll
                for (int it = 0; it < 4; it++) {
                    const int row = it * 64 + sr2;   // d row
                    *(int4*)&smV[row * 40 + sc2] =
                        *(const int4*)(Vb + (size_t)row * 1024 + kt * 128 + kc * 32 + sc2);
                }
                __syncthreads();
                const bf16x8_t pa = *(const bf16x8_t*)&Pw[fr * 136 + kc * 32 + qd * 8];
#pragma unroll
                for (int df = 0; df < 16; df++) {
                    bf16x8_t vb = *(const bf16x8_t*)&smV[(df * 16 + fr) * 40 + qd * 8];
                    Op[df] = __builtin_amdgcn_mfma_f32_16x16x32_bf16(pa, vb, Op[df], 0, 0, 0);
                }
            }
        }
        // ---- normalize, store Msg piece p via LDS transpose ----
        float invl[4];
#pragma unroll
        for (int r = 0; r < 4; r++) invl[r] = 1.0f / lrun[r];
        float* outb = Msg + ((size_t)p * 3 + m) * BND_ + (size_t)batch * N_ * D_
                    + (size_t)(qt * 64 + w * 16) * D_;
        __syncthreads();   // P reads done before region reuse
#pragma unroll
        for (int ch = 0; ch < 4; ch++) {
#pragma unroll
            for (int jj = 0; jj < 4; jj++)
#pragma unroll
                for (int r = 0; r < 4; r++)
                    Ew[(qd * 4 + r) * EPI_S + jj * 16 + fr] = Op[ch * 4 + jj][r] * invl[r];
            __syncthreads();
#pragma unroll
            for (int t = 0; t < 4; t++) {
                const int lrow = t * 4 + qd;
                const f32x4_t v4 = *(const f32x4_t*)&Ew[lrow * EPI_S + fr * 4];
                *(f32x4_t*)(outb + (size_t)lrow * D_ + ch * 64 + fr * 4) = v4;
            }
            __syncthreads();
        }
    }
}

// ---------------------------------------------------------------------------
// Weight convert+transpose, all 5 weights in one dispatch (z selects).
// ---------------------------------------------------------------------------
__global__ __launch_bounds__(256) void wt_transpose_kernel(
    const float* __restrict__ W0, const float* __restrict__ W1,
    const float* __restrict__ W2, const float* __restrict__ W3,
    const float* __restrict__ W4, __hip_bfloat16* __restrict__ out)
{
    const int z = blockIdx.z;
    const float* in = z == 0 ? W0 : z == 1 ? W1 : z == 2 ? W2 : z == 3 ? W3 : W4;
    __hip_bfloat16* o = out + (size_t)z * D_ * D_;
    __shared__ float t[32][33];
    const int r0 = blockIdx.x * 32, c0 = blockIdx.y * 32;
    const int tx = threadIdx.x & 31, ty = threadIdx.x >> 5;
#pragma unroll
    for (int k = 0; k < 4; k++) {
        int r = ty + k * 8;
        t[r][tx] = in[(size_t)(r0 + r) * D_ + (c0 + tx)];
    }
    __syncthreads();
#pragma unroll
    for (int k = 0; k < 4; k++) {
        int r = ty + k * 8;
        o[(size_t)(c0 + r) * D_ + (r0 + tx)] = __float2bfloat16(t[tx][r]);
    }
}

// bf16 transpose for V: out[c][r] = in[r][c], batched over z.
__global__ __launch_bounds__(256) void transpose_bf16_kernel(
    const __hip_bfloat16* __restrict__ in, __hip_bfloat16* __restrict__ out,
    int R, int Cc, long long sIn, long long sOut)
{
    __shared__ short t[32][33];
    const size_t bz = blockIdx.z;
    const short* I = (const short*)in + bz * (size_t)sIn;
    short* O = (short*)out + bz * (size_t)sOut;
    const int r0 = blockIdx.x * 32, c0 = blockIdx.y * 32;
    const int tx = threadIdx.x & 31, ty = threadIdx.x >> 5;
#pragma unroll
    for (int k = 0; k < 4; k++) {
        int r = ty + k * 8;
        t[r][tx] = I[(size_t)(r0 + r) * Cc + (c0 + tx)];
    }
    __syncthreads();
#pragma unroll
    for (int k = 0; k < 4; k++) {
        int r = ty + k * 8;
        O[(size_t)(c0 + r) * R + (r0 + tx)] = t[tx][r];
    }
}

// all 3 modality inputs fp32 -> bf16, one dispatch
__global__ void cvt3_kernel(const float* __restrict__ x0, const float* __restrict__ x1,
                            const float* __restrict__ x2, __hip_bfloat16* __restrict__ dst)
{
    const int z = blockIdx.z;
    const float* s = z == 0 ? x0 : z == 1 ? x1 : x2;
    const long long i = (long long)blockIdx.x * 256 + threadIdx.x;
    dst[(size_t)z * BND_ + i] = __float2bfloat16(s[i]);
}

__global__ void zero_kernel(float* __restrict__ p, int n)
{
    const int i = blockIdx.x * 256 + threadIdx.x;
    if (i < n) p[i] = 0.0f;
}

// ---------------------------------------------------------------------------
// Hypergraph pipeline, batched over 3 modalities via blockIdx.z
// ---------------------------------------------------------------------------
__global__ void hg_count_kernel(const int* __restrict__ i0, const int* __restrict__ i1,
                                const int* __restrict__ i2,
                                int* __restrict__ Ddeg, int* __restrict__ Edeg)
{
    const int z = blockIdx.z;
    const int* idx = z == 0 ? i0 : z == 1 ? i1 : i2;
    const int c = blockIdx.x * 256 + threadIdx.x;
    atomicAdd(&Ddeg[z * N_ + idx[c]], 1);
    atomicAdd(&Edeg[z * M_ + idx[C_ + c]], 1);
}

__global__ __launch_bounds__(1024) void hg_scan_kernel(
    const int* __restrict__ deg, int* __restrict__ offs,
    float* __restrict__ inv, int* __restrict__ cnt, int len)
{
    const int z = blockIdx.z;
    deg += z * len; offs += z * (len + 1); inv += z * len; cnt += z * len;
    __shared__ int tmp[1024];
    const int t = threadIdx.x;
    const int v = deg[t];
    tmp[t] = v;
    __syncthreads();
    for (int o = 1; o < len; o <<= 1) {
        int x = (t >= o) ? tmp[t - o] : 0;
        __syncthreads();
        tmp[t] += x;
        __syncthreads();
    }
    offs[t] = tmp[t] - v;
    if (t == len - 1) offs[len] = tmp[t];
    inv[t] = (v > 0) ? (1.0f / (float)v) : 0.0f;
    cnt[t] = 0;
}

__global__ void hg_fill_kernel(const int* __restrict__ i0, const int* __restrict__ i1,
                               const int* __restrict__ i2,
                               const int* __restrict__ noffs, const int* __restrict__ eoffs,
                               int* __restrict__ ncnt, int* __restrict__ ecnt,
                               int* __restrict__ nord, int* __restrict__ eord)
{
    const int z = blockIdx.z;
    const int* nidx = z == 0 ? i0 : z == 1 ? i1 : i2;
    const int* eidx = nidx + C_;
    noffs += z * (N_ + 1); eoffs += z * (M_ + 1);
    ncnt += z * N_; ecnt += z * M_; nord += z * C_; eord += z * C_;
    const int c = blockIdx.x * 256 + threadIdx.x;
    const int nd = nidx[c], ed = eidx[c];
    const int p1 = atomicAdd(&ncnt[nd], 1);
    nord[noffs[nd] + p1] = c;
    const int p2 = atomicAdd(&ecnt[ed], 1);
    eord[eoffs[ed] + p2] = c;
}

// s1/s2 from bf16 xp; one wave per (md,b,n)
__global__ __launch_bounds__(64) void hg_s12_kernel(
    const unsigned short* __restrict__ Xp, const float* __restrict__ att,
    float* __restrict__ s1, float* __restrict__ s2)
{
    const int z = blockIdx.z;
    const int bid = blockIdx.x;
    const int b = bid >> 10;
    const int n = bid & (N_ - 1);
    const int lane = threadIdx.x;
    const unsigned short* xr = Xp + (size_t)z * BND_ + (size_t)(b * N_ + n) * D_;
    const ushort4 u = ((const ushort4*)xr)[lane];
    const float4 a1 = ((const float4*)att)[lane];
    const float4 a2 = ((const float4*)(att + D_))[lane];
    float d1 = bf2f(u.x) * a1.x + bf2f(u.y) * a1.y + bf2f(u.z) * a1.z + bf2f(u.w) * a1.w;
    float d2 = bf2f(u.x) * a2.x + bf2f(u.y) * a2.y + bf2f(u.z) * a2.z + bf2f(u.w) * a2.w;
#pragma unroll
    for (int o = 32; o > 0; o >>= 1) { d1 += __shfl_down(d1, o); d2 += __shfl_down(d2, o); }
    if (lane == 0) { s1[z * NB_ + n * 16 + b] = d1; s2[z * NB_ + n * 16 + b] = d2; }
}

// edge_s2[m,b]: atomic-free, grid (M_,1,3), 16 pos x 16 b LDS reduce.
__global__ __launch_bounds__(256) void hg_edge_s2_kernel(
    const int* __restrict__ i0, const int* __restrict__ i1, const int* __restrict__ i2,
    const int* __restrict__ eoffs, const int* __restrict__ eord,
    const float* __restrict__ s2, float* __restrict__ edge_s2)
{
    const int z = blockIdx.z;
    const int* nidx = z == 0 ? i0 : z == 1 ? i1 : i2;
    eoffs += z * (M_ + 1); eord += z * C_;
    s2 += z * NB_; edge_s2 += (size_t)z * M_ * 16;

    const int m = blockIdx.x;
    const int pos = threadIdx.x >> 4;
    const int b = threadIdx.x & 15;
    const int base = eoffs[m];
    const int len = eoffs[m + 1] - base;
    float acc = 0.0f;
#pragma unroll 4
    for (int i = pos; i < len; i += 16) {
        int c = eord[base + i];
        acc += s2[nidx[c] * 16 + b];
    }
    __shared__ float red[16][16];
    red[pos][b] = acc;
    __syncthreads();
    for (int s = 8; s > 0; s >>= 1) {
        if (pos < s) red[pos][b] += red[pos + s][b];
        __syncthreads();
    }
    if (pos == 0) edge_s2[m * 16 + b] = red[0][b];
}

__global__ __launch_bounds__(256) void hg_node_softmax_kernel(
    const int* __restrict__ i0, const int* __restrict__ i1, const int* __restrict__ i2,
    const int* __restrict__ noffs, const int* __restrict__ nord,
    const float* __restrict__ s1, const float* __restrict__ edge_s2,
    float* __restrict__ ee, float* __restrict__ inv_sum)
{
    const int z = blockIdx.z;
    const int* eidx = (z == 0 ? i0 : z == 1 ? i1 : i2) + C_;
    noffs += z * (N_ + 1); nord += z * C_;
    s1 += z * NB_; edge_s2 += (size_t)z * M_ * 16;
    ee += (size_t)z * C_ * 16; inv_sum += z * NB_;

    const int n = blockIdx.x;
    const int base = noffs[n];
    const int len = noffs[n + 1] - base;
    if (len == 0) return;
    const int cp = threadIdx.x >> 4;
    const int b = threadIdx.x & 15;
    __shared__ float red[16][16];
    const float s1nb = s1[n * 16 + b];

    float mx = -1e30f;
    for (int i = cp; i < len; i += 16) {
        int c = nord[base + i];
        float e = s1nb + edge_s2[eidx[c] * 16 + b];
        e = e > 0.0f ? e : 0.2f * e;      // leaky_relu 0.2
        mx = fmaxf(mx, e);
    }
    red[cp][b] = mx;
    __syncthreads();
    for (int s = 8; s > 0; s >>= 1) {
        if (cp < s) red[cp][b] = fmaxf(red[cp][b], red[cp + s][b]);
        __syncthreads();
    }
    mx = red[0][b];
    __syncthreads();

    float sm = 0.0f;
    for (int i = cp; i < len; i += 16) {
        int c = nord[base + i];
        float e = s1nb + edge_s2[eidx[c] * 16 + b];
        e = e > 0.0f ? e : 0.2f * e;
        float ex = __expf(e - mx);
        ee[c * 16 + b] = ex;
        sm += ex;
    }
    red[cp][b] = sm;
    __syncthreads();
    for (int s = 8; s > 0; s >>= 1) {
        if (cp < s) red[cp][b] += red[cp + s][b];
        __syncthreads();
    }
    if (cp == 0) inv_sum[n * 16 + b] = 1.0f / (red[0][b] + 1e-16f);
}

// Pack sorted-order gather arrays (kills dependent chains in xedge/xnode).
__global__ __launch_bounds__(256) void hg_pack_kernel(
    const int* __restrict__ i0, const int* __restrict__ i1, const int* __restrict__ i2,
    const int* __restrict__ nord, const int* __restrict__ eord,
    const float* __restrict__ ee, const float* __restrict__ inv_sum,
    int* __restrict__ EmS, int* __restrict__ NnS,
    float* __restrict__ CoefN, float* __restrict__ CoefE)
{
    const int z = blockIdx.z;
    const int* nidx = z == 0 ? i0 : z == 1 ? i1 : i2;
    const int* eidx = nidx + C_;
    nord += z * C_; eord += z * C_;
    ee += (size_t)z * C_ * 16; inv_sum += z * NB_;
    EmS += z * C_; NnS += z * C_;
    CoefN += (size_t)z * C_ * 16; CoefE += (size_t)z * C_ * 16;

    const int gid = blockIdx.x * 256 + threadIdx.x;   // C*16
    const int i = gid >> 4, b = gid & 15;
    const int c1 = nord[i], c2 = eord[i];
    const int n1 = nidx[c1], n2 = nidx[c2];
    if (b == 0) { EmS[i] = eidx[c1]; NnS[i] = n2; }
    CoefN[i * 16 + b] = ee[c1 * 16 + b] * inv_sum[n1 * 16 + b];
    CoefE[i * 16 + b] = ee[c2 * 16 + b] * inv_sum[n2 * 16 + b];
}

// x_edge[m,b,:] via packed arrays.
__global__ __launch_bounds__(256) void hg_xedge_kernel(
    const int* __restrict__ eoffs, const int* __restrict__ NnS,
    const float* __restrict__ CoefE, const unsigned short* __restrict__ Xp,
    const float* __restrict__ Bnorm, float* __restrict__ x_edge)
{
    const int z = blockIdx.z;
    eoffs += z * (M_ + 1); NnS += z * C_;
    CoefE += (size_t)z * C_ * 16;
    const unsigned short* xp = Xp + (size_t)z * BND_;
    Bnorm += z * M_; x_edge += (size_t)z * M_ * B_ * D_;

    const int m = blockIdx.x >> 4;
    const int b = blockIdx.x & 15;
    const int d = threadIdx.x;
    const int base = eoffs[m];
    const int len = eoffs[m + 1] - base;
    float acc = 0.0f;
#pragma unroll 4
    for (int i = 0; i < len; i++) {
        const int nn = NnS[base + i];
        const float cf = CoefE[(size_t)(base + i) * 16 + b];
        acc += cf * bf2f(xp[(size_t)(b * N_ + nn) * D_ + d]);
    }
    x_edge[((size_t)(m * 16 + b)) * D_ + d] = Bnorm[m] * acc;
}

// h[b,n,:] via packed arrays.
__global__ __launch_bounds__(256) void hg_xnode_kernel(
    const int* __restrict__ noffs, const int* __restrict__ EmS,
    const float* __restrict__ CoefN, const float* __restrict__ x_edge,
    const float* __restrict__ Dinv, __hip_bfloat16* __restrict__ Hbf)
{
    const int z = blockIdx.z;
    noffs += z * (N_ + 1); EmS += z * C_;
    CoefN += (size_t)z * C_ * 16;
    x_edge += (size_t)z * M_ * B_ * D_; Dinv += z * N_;
    __hip_bfloat16* hbf = Hbf + (size_t)z * BND_;

    const int n = blockIdx.x >> 4;
    const int b = blockIdx.x & 15;
    const int d = threadIdx.x;
    const int base = noffs[n];
    const int len = noffs[n + 1] - base;
    float acc = 0.0f;
#pragma unroll 4
    for (int i = 0; i < len; i++) {
        const int em = EmS[base + i];
        const float cf = CoefN[(size_t)(base + i) * 16 + b];
        acc += cf * x_edge[((size_t)(em * 16 + b)) * D_ + d];
    }
    hbf[((size_t)(b * N_ + n)) * D_ + d] = __float2bfloat16(Dinv[n] * acc);
}

// ---------------------------------------------------------------------------
// Host
// ---------------------------------------------------------------------------
static inline void launch_gemm(hipStream_t s, dim3 grid,
                               const void* A0, const void* A1, int lda, long long sA,
                               const void* B0, const void* B1, int ldb, long long sB,
                               void* Cv, int ldc, long long sC, long long cOff, long long pieceCs,
                               int K, int kPiece, int zBatches,
                               float scale, const float* bias,
                               const float* a0, const float* a1, int epi)
{
    gemm_nt_kernel<<<grid, 256, 0, s>>>((const __hip_bfloat16*)A0, (const __hip_bfloat16*)A1,
                                        lda, sA,
                                        (const __hip_bfloat16*)B0, (const __hip_bfloat16*)B1,
                                        ldb, sB,
                                        Cv, ldc, sC, cOff, pieceCs, K, kPiece, zBatches,
                                        scale, bias, a0, a1, epi);
}

extern "C" void kernel_launch(void* const* d_in, const int* in_sizes, int n_in,
                              void* d_out, int out_size, void* d_ws, size_t ws_size,
                              hipStream_t stream)
{
    (void)in_sizes; (void)n_in; (void)out_size; (void)ws_size;

    const float* x0 = (const float*)d_in[0];
    const float* x1 = (const float*)d_in[1];
    const float* x2 = (const float*)d_in[2];
    const int* h0 = (const int*)d_in[3];
    const int* h1 = (const int*)d_in[4];
    const int* h2 = (const int*)d_in[5];
    const float* W_hg  = (const float*)d_in[6];
    const float* att_hg= (const float*)d_in[7];
    const float* WQ = (const float*)d_in[8];
    const float* bQ = (const float*)d_in[9];
    const float* WK = (const float*)d_in[10];
    const float* bK = (const float*)d_in[11];
    const float* WV = (const float*)d_in[12];
    const float* bV = (const float*)d_in[13];
    const float* WO = (const float*)d_in[14];
    const float* bO = (const float*)d_in[15];
    float* outp = (float*)d_out;

    char* ws = (char*)d_ws;
    size_t off = 0;
    auto take = [&](size_t bytes) { size_t r = off; off += (bytes + 255) & ~(size_t)255; return r; };

    const size_t oWt   = take((size_t)5 * D_ * D_ * 2);          // 0.63 MB
    const size_t oHbf  = take((size_t)3 * BND_ * 2);             // 24 MB
    const size_t oKall = take((size_t)3 * BND_ * 2);             // 24 MB
    const size_t oVt   = take((size_t)3 * BND_ * 2);             // 24 MB
    const size_t oQall = take((size_t)3 * BND_ * 2);             // 24 MB
    const size_t oBIG  = take((size_t)6 * BND_ * 4);             // 96 MB: Xc+Xp | Vtmp | Msg(2 pieces)
    const size_t oXe   = take((size_t)3 * M_ * B_ * D_ * 4);     // 6 MB
    const size_t oEE   = take((size_t)3 * C_ * 16 * 4);
    const size_t oCoefN= take((size_t)3 * C_ * 16 * 4);
    const size_t oCoefE= take((size_t)3 * C_ * 16 * 4);
    const size_t oEmS  = take((size_t)3 * C_ * 4);
    const size_t oNnS  = take((size_t)3 * C_ * 4);
    const size_t oS1   = take((size_t)3 * NB_ * 4);
    const size_t oS2   = take((size_t)3 * NB_ * 4);
    const size_t oInv  = take((size_t)3 * NB_ * 4);
    const size_t oZero = take((size_t)3 * (N_ + M_) * 4);
    const size_t oEs2  = take((size_t)3 * M_ * 16 * 4);
    const size_t oNOffs= take((size_t)3 * (N_ + 1) * 4);
    const size_t oEOffs= take((size_t)3 * (M_ + 1) * 4);
    const size_t oNCnt = take((size_t)3 * N_ * 4);
    const size_t oECnt = take((size_t)3 * M_ * 4);
    const size_t oNOrd = take((size_t)3 * C_ * 4);
    const size_t oEOrd = take((size_t)3 * C_ * 4);
    const size_t oDinv = take((size_t)3 * N_ * 4);
    const size_t oBnorm= take((size_t)3 * M_ * 4);

    __hip_bfloat16* Wt   = (__hip_bfloat16*)(ws + oWt);
    __hip_bfloat16* Hbf  = (__hip_bfloat16*)(ws + oHbf);
    __hip_bfloat16* Kall = (__hip_bfloat16*)(ws + oKall);
    __hip_bfloat16* Vt   = (__hip_bfloat16*)(ws + oVt);
    __hip_bfloat16* Qall = (__hip_bfloat16*)(ws + oQall);
    // BIG union: phase1 Xc@+0 (24) + Xp@+24 (24); phase2 Vtmp@+0; phase3 Msg 2x48
    __hip_bfloat16* Xc   = (__hip_bfloat16*)(ws + oBIG);
    __hip_bfloat16* Xp   = (__hip_bfloat16*)(ws + oBIG + (size_t)3 * BND_ * 2);
    __hip_bfloat16* Vtmp = (__hip_bfloat16*)(ws + oBIG);
    float* Msg  = (float*)(ws + oBIG);
    float* Xe   = (float*)(ws + oXe);
    float* EE   = (float*)(ws + oEE);
    float* CoefN= (float*)(ws + oCoefN);
    float* CoefE= (float*)(ws + oCoefE);
    int*   EmS  = (int*)(ws + oEmS);
    int*   NnS  = (int*)(ws + oNnS);
    float* S1f  = (float*)(ws + oS1);
    float* S2f  = (float*)(ws + oS2);
    float* Inv  = (float*)(ws + oInv);
    int*   Ddeg = (int*)(ws + oZero);
    int*   Edeg = (int*)(ws + oZero + (size_t)3 * N_ * 4);
    float* Es2  = (float*)(ws + oEs2);
    const int zeroWords = 3 * (N_ + M_);
    int*   NOffs = (int*)(ws + oNOffs);
    int*   EOffs = (int*)(ws + oEOffs);
    int*   NCnt  = (int*)(ws + oNCnt);
    int*   ECnt  = (int*)(ws + oECnt);
    int*   NOrd  = (int*)(ws + oNOrd);
    int*   EOrd  = (int*)(ws + oEOrd);
    float* Dinv  = (float*)(ws + oDinv);
    float* Bnorm = (float*)(ws + oBnorm);

    const int WN = D_ * D_;
    __hip_bfloat16* WtHG = Wt;
    __hip_bfloat16* WtQ  = Wt + (size_t)WN;
    __hip_bfloat16* WtK  = Wt + (size_t)2 * WN;
    __hip_bfloat16* WtV  = Wt + (size_t)3 * WN;
    __hip_bfloat16* WtO  = Wt + (size_t)4 * WN;

    // -------- Phase 0: weights (one dispatch) -------------------------------
    wt_transpose_kernel<<<dim3(8, 8, 5), 256, 0, stream>>>(W_hg, WQ, WK, WV, WO, Wt);

    // -------- Phase 1: hypergraph conv, all modalities batched --------------
    cvt3_kernel<<<dim3((unsigned)(BND_ / 256), 1, 3), 256, 0, stream>>>(x0, x1, x2, Xc);
    zero_kernel<<<(zeroWords + 255) / 256, 256, 0, stream>>>((float*)(ws + oZero), zeroWords);
    hg_count_kernel<<<dim3(C_ / 256, 1, 3), 256, 0, stream>>>(h0, h1, h2, Ddeg, Edeg);
    hg_scan_kernel<<<dim3(1, 1, 3), N_, 0, stream>>>(Ddeg, NOffs, Dinv, NCnt, N_);
    hg_scan_kernel<<<dim3(1, 1, 3), M_, 0, stream>>>(Edeg, EOffs, Bnorm, ECnt, M_);
    hg_fill_kernel<<<dim3(C_ / 256, 1, 3), 256, 0, stream>>>(h0, h1, h2, NOffs, EOffs,
                                                             NCnt, ECnt, NOrd, EOrd);
    launch_gemm(stream, dim3(BN_ / 128, D_ / 128, 3),
                Xc, Xc, D_, BND_, WtHG, WtHG, D_, 0,
                Xp, D_, BND_, 0, 0, D_, D_, 3,
                1.0f, nullptr, nullptr, nullptr, 1);
    hg_s12_kernel<<<dim3(BN_, 1, 3), 64, 0, stream>>>((const unsigned short*)Xp, att_hg, S1f, S2f);
    hg_edge_s2_kernel<<<dim3(M_, 1, 3), 256, 0, stream>>>(h0, h1, h2, EOffs, EOrd, S2f, Es2);
    hg_node_softmax_kernel<<<dim3(N_, 1, 3), 256, 0, stream>>>(h0, h1, h2, NOffs, NOrd,
                                                               S1f, Es2, EE, Inv);
    hg_pack_kernel<<<dim3(C_ * 16 / 256, 1, 3), 256, 0, stream>>>(h0, h1, h2, NOrd, EOrd,
                                                                  EE, Inv, EmS, NnS, CoefN, CoefE);
    hg_xedge_kernel<<<dim3(M_ * B_, 1, 3), 256, 0, stream>>>(EOffs, NnS, CoefE,
                                                             (const unsigned short*)Xp, Bnorm, Xe);
    hg_xnode_kernel<<<dim3(N_ * B_, 1, 3), 256, 0, stream>>>(NOffs, EmS, CoefN, Xe, Dinv, Hbf);

    // -------- Phase 2: K, V, Q for all 3 modalities -------------------------
    launch_gemm(stream, dim3(3 * BN_ / 128, D_ / 128, 1),
                Hbf, Hbf, D_, 0, WtK, WtK, D_, 0,
                Kall, D_, 0, 0, 0, D_, D_, 1,
                1.0f, bK, nullptr, nullptr, 1);
    launch_gemm(stream, dim3(3 * BN_ / 128, D_ / 128, 1),
                Hbf, Hbf, D_, 0, WtV, WtV, D_, 0,
                Vtmp, D_, 0, 0, 0, D_, D_, 1,
                1.0f, bV, nullptr, nullptr, 1);
    transpose_bf16_kernel<<<dim3(N_ / 32, D_ / 32, 48), 256, 0, stream>>>(
        Vtmp, Vt, N_, D_, (long long)N_ * D_, (long long)D_ * N_);
    launch_gemm(stream, dim3(3 * BN_ / 128, D_ / 128, 1),
                Hbf, Hbf, D_, 0, WtQ, WtQ, D_, 0,
                Qall, D_, 0, 0, 0, D_, D_, 1,
                0.0625f, bQ, nullptr, nullptr, 4);

    // -------- Phase 3: fused flash attention + output -----------------------
    flash_attn_kernel<<<dim3(N_ / 64, B_, 3), 256, 0, stream>>>(Qall, Kall, Vt, Msg);
    launch_gemm(stream, dim3(BN_ / 128, D_ / 128, 3),
                Hbf, Hbf, D_, BND_, WtO, WtO, D_, 0,
                outp, D_, BND_, 0, 0, D_, D_, 3,
                1.0f, bO, Msg, Msg + (size_t)3 * BND_, 2);
}